// Round 1
// baseline (2369.416 us; speedup 1.0000x reference)
//
#include <hip/hip_runtime.h>
#include <cmath>

#define B_ 1024
#define CIN_ 22
#define T1_ 438
#define COUT_ 20
#define T2_ 439

// ws float offsets (total ~23 MB required)
#define OFF_S 0
#define OFF_M 32
#define OFF_A1 520
#define OFF_E1 544
#define OFF_SUM2 576
#define OFF_SSQ2 608
#define OFF_A2 640
#define OFF_ACC_END 704
#define OFF_C 1024
#define OFF_LQ (OFF_C + B_*3*400)
#define OFF_LK (OFF_LQ + B_*3*324)
#define OFF_LV (OFF_LK + B_*3*324)
#define OFF_ML (OFF_LV + B_*3*324)
#define OFF_FEAT (OFF_ML + B_*3*324)
#define WS_FLOATS (OFF_FEAT + B_*513)

__global__ __launch_bounds__(256) void k_zero(float* ws){
  for(int i=threadIdx.x; i<OFF_ACC_END; i+=256) ws[i]=0.f;
}

// bn1 stats via second-moment matrix of x: S[22], M[22][22] (triu)
__global__ __launch_bounds__(256) void k_moment(const float* __restrict__ x, float* __restrict__ ws){
  __shared__ float xs[CIN_*T1_];
  int b=blockIdx.x;
  const float* xb = x + (size_t)b*CIN_*T1_;
  for(int i=threadIdx.x;i<CIN_*T1_;i+=256) xs[i]=xb[i];
  __syncthreads();
  for(int tgt=threadIdx.x; tgt<275; tgt+=256){
    if(tgt<253){
      int r=tgt, i=0;
      while(true){ int c=CIN_-i; if(r<c) break; r-=c; i++; }
      int j=i+r;
      const float* ri=xs+i*T1_; const float* rj=xs+j*T1_;
      float acc=0.f;
      for(int t=0;t<T1_;t++) acc += ri[t]*rj[t];
      atomicAdd(&ws[OFF_M + i*CIN_ + j], acc);
    } else {
      int c=tgt-253;
      const float* rc=xs+c*T1_;
      float acc=0.f;
      for(int t=0;t<T1_;t++) acc += rc[t];
      atomicAdd(&ws[OFF_S + c], acc);
    }
  }
}

__global__ void k_fin1(const float* __restrict__ w1, const float* __restrict__ cb1,
                       const float* __restrict__ g1, const float* __restrict__ bb1,
                       float* __restrict__ ws){
  int c=threadIdx.x;
  if(c>=CIN_) return;
  const double N = (double)B_*T1_;
  double wS=0.0, wMw=0.0;
  for(int h=0;h<CIN_;h++) wS += (double)w1[c*CIN_+h]*(double)ws[OFF_S+h];
  for(int h=0;h<CIN_;h++){
    for(int h2=0;h2<CIN_;h2++){
      int i=h<h2?h:h2, j=h<h2?h2:h;
      wMw += (double)w1[c*CIN_+h]*(double)w1[c*CIN_+h2]*(double)ws[OFF_M+i*CIN_+j];
    }
  }
  double bc=cb1[c];
  double mean=wS/N+bc;
  double ex2=(wMw+2.0*bc*wS)/N+bc*bc;
  double var=ex2-mean*mean;
  double a1=(double)g1[c]/sqrt(var+1e-5);
  double d1=(double)bb1[c]-mean*a1;
  ws[OFF_A1+c]=(float)a1;            // y = a1*conv1 + e1
  ws[OFF_E1+c]=(float)(a1*bc+d1);
}

// per-batch: y = bn1(conv1(x)); h2 = conv2(y); raw patch covariances + bn2 sums
__global__ __launch_bounds__(256) void k_conv2cov(const float* __restrict__ x,
                                                  const float* __restrict__ w1,
                                                  const float* __restrict__ w2,
                                                  float* __restrict__ ws){
  __shared__ float yw[CIN_][160];
  __shared__ float h2w[COUT_][148];
  __shared__ float w2s[COUT_*CIN_*12];
  __shared__ float w1s[CIN_*CIN_];
  __shared__ float a1s[CIN_], e1s[CIN_];
  __shared__ float acc1[COUT_], acc2[COUT_], pmu[COUT_];
  int b=blockIdx.x, tid=threadIdx.x;
  for(int i=tid;i<COUT_*CIN_*12;i+=256) w2s[i]=w2[i];
  for(int i=tid;i<CIN_*CIN_;i+=256) w1s[i]=w1[i];
  if(tid<CIN_){ a1s[tid]=ws[OFF_A1+tid]; e1s[tid]=ws[OFF_E1+tid]; }
  if(tid<COUT_){ acc1[tid]=0.f; acc2[tid]=0.f; }
  __syncthreads();
  for(int p=0;p<3;p++){
    int off = (p==0)?0:((p==1)?147:293);
    int L = (p==0)?147:146;
    int ycols = L+11;
    int ybase = off-6;
    for(int idx=tid; idx<CIN_*ycols; idx+=256){
      int c=idx/ycols, tt=idx-c*ycols, gt=ybase+tt;
      float v=0.f;
      if(gt>=0 && gt<T1_){
        const float* xb=x+(size_t)b*CIN_*T1_+gt;
        float s=0.f;
        for(int h=0;h<CIN_;h++) s += w1s[c*CIN_+h]*xb[(size_t)h*T1_];
        v = a1s[c]*s + e1s[c];
      }
      yw[c][tt]=v;
    }
    __syncthreads();
    for(int idx=tid; idx<COUT_*L; idx+=256){
      int o=idx/L, tt=idx-o*L;
      float s=0.f;
      for(int i=0;i<CIN_;i++){
        const float* wo=&w2s[(o*CIN_+i)*12];
        const float* yr=&yw[i][tt];
        #pragma unroll
        for(int k=0;k<12;k++) s += wo[k]*yr[k];
      }
      h2w[o][tt]=s;
    }
    __syncthreads();
    if(tid<COUT_){
      float s1=0.f,s2=0.f;
      for(int t=0;t<L;t++){ float v=h2w[tid][t]; s1+=v; s2+=v*v; }
      acc1[tid]+=s1; acc2[tid]+=s2; pmu[tid]=s1/(float)L;
    }
    __syncthreads();
    float* Cb = ws + OFF_C + ((size_t)b*3+p)*400;
    for(int pp=tid; pp<210; pp+=256){
      int r=pp, i=0;
      while(true){ int c=COUT_-i; if(r<c) break; r-=c; i++; }
      int j=i+r;
      float s=0.f;
      for(int t=0;t<L;t++) s += h2w[i][t]*h2w[j][t];
      s -= (float)L*pmu[i]*pmu[j];
      Cb[i*COUT_+j]=s;
      Cb[j*COUT_+i]=s;
    }
    __syncthreads();
  }
  if(tid<COUT_){
    atomicAdd(&ws[OFF_SUM2+tid], acc1[tid]);
    atomicAdd(&ws[OFF_SSQ2+tid], acc2[tid]);
  }
}

__global__ void k_fin2(const float* __restrict__ g2, float* __restrict__ ws){
  int c=threadIdx.x; if(c>=COUT_) return;
  const double N=(double)B_*T2_;
  double m=ws[OFF_SUM2+c]/N;
  double v=ws[OFF_SSQ2+c]/N - m*m;
  ws[OFF_A2+c]=(float)((double)g2[c]/sqrt(v+1e-5));
}

// parallel-order Jacobi eigendecomposition, 18x18, one wave (64 threads)
__device__ __forceinline__ void jacobi18(float (*A)[19], float (*V)[19],
                                         float* cc, float* bb, int* pr, int tid){
  #pragma unroll
  for(int u=0;u<6;u++){
    int idx=tid+u*64;
    if(idx<324){ int i=idx/18, j=idx-i*18; V[i][j]=(i==j)?1.f:0.f; }
  }
  __syncthreads();
  for(int sweep=0; sweep<16; sweep++){
    for(int r=0;r<17;r++){
      if(tid<9){
        int p,q;
        if(tid==0){ p=17; q=r; }
        else { p=(r+tid)%17; q=(r+17-tid)%17; }
        if(p>q){ int t=p; p=q; q=t; }
        float app=A[p][p], aqq=A[q][q], apq=A[p][q];
        float c=1.f, s=0.f;
        if(apq!=0.f){
          float tau=(aqq-app)/(2.f*apq);
          float t=copysignf(1.f,tau)/(fabsf(tau)+sqrtf(1.f+tau*tau));
          c=1.f/sqrtf(1.f+t*t);
          s=t*c;
        }
        cc[p]=c; cc[q]=c; bb[p]=-s; bb[q]=s; pr[p]=q; pr[q]=p;
      }
      __syncthreads();
      float rA[6], rV[6];
      #pragma unroll
      for(int u=0;u<6;u++){
        int idx=tid+u*64;
        if(idx<324){
          int i=idx/18, j=idx-i*18; int m=pr[j];
          rA[u]=cc[j]*A[i][j]+bb[j]*A[i][m];
          rV[u]=cc[j]*V[i][j]+bb[j]*V[i][m];
        }
      }
      __syncthreads();
      #pragma unroll
      for(int u=0;u<6;u++){
        int idx=tid+u*64;
        if(idx<324){ int i=idx/18, j=idx-i*18; A[i][j]=rA[u]; V[i][j]=rV[u]; }
      }
      __syncthreads();
      #pragma unroll
      for(int u=0;u<6;u++){
        int idx=tid+u*64;
        if(idx<324){
          int i=idx/18, j=idx-i*18; int m=pr[i];
          rA[u]=cc[i]*A[i][j]+bb[i]*A[m][j];
        }
      }
      __syncthreads();
      #pragma unroll
      for(int u=0;u<6;u++){
        int idx=tid+u*64;
        if(idx<324){ int i=idx/18, j=idx-i*18; A[i][j]=rA[u]; }
      }
      __syncthreads();
    }
    float off=0.f, dg=0.f;
    #pragma unroll
    for(int u=0;u<6;u++){
      int idx=tid+u*64;
      if(idx<324){
        int i=idx/18, j=idx-i*18; float v=A[i][j];
        if(i==j) dg+=v*v; else off+=v*v;
      }
    }
    for(int o=32;o>0;o>>=1){ off+=__shfl_down(off,o); dg+=__shfl_down(dg,o); }
    off=__shfl(off,0); dg=__shfl(dg,0);
    if(off<=1e-14f*dg) break;
  }
}

// scale C by a2, trace-normalize, +1e-5 I, congruence with W, logm -> store
__global__ __launch_bounds__(64) void k_eighQKV(const float* __restrict__ Wq,
                                                const float* __restrict__ Wk,
                                                const float* __restrict__ Wv,
                                                float* __restrict__ ws){
  __shared__ float Cm[20][21];
  __shared__ float T1s[18][21];
  __shared__ float A[18][19];
  __shared__ float V[18][19];
  __shared__ float cc[18], bb[18];
  __shared__ int pr[18];
  __shared__ float invtr_s;
  int blk=blockIdx.x, tid=threadIdx.x;
  int b=blk/9, rem=blk-b*9;
  int p=rem/3, m=rem-p*3;
  const float* W = (m==0)?Wq:((m==1)?Wk:Wv);
  const float* Cb = ws + OFF_C + ((size_t)b*3+p)*400;
  const float* a2 = ws + OFF_A2;
  for(int idx=tid; idx<400; idx+=64){
    int i=idx/20, j=idx-i*20;
    Cm[i][j]=Cb[idx]*a2[i]*a2[j];
  }
  __syncthreads();
  if(tid==0){
    float tr=0.f;
    for(int i=0;i<20;i++) tr+=Cm[i][i];
    invtr_s=1.f/tr;
  }
  __syncthreads();
  float invtr=invtr_s;
  for(int idx=tid; idx<360; idx+=64){
    int a=idx/20, j=idx-a*20;
    float s=0.f;
    for(int i=0;i<20;i++){
      float cij=Cm[i][j]*invtr + ((i==j)?1e-5f:0.f);
      s += W[i*18+a]*cij;
    }
    T1s[a][j]=s;
  }
  __syncthreads();
  for(int idx=tid; idx<324; idx+=64){
    int a=idx/18, c2=idx-a*18;
    float s=0.f;
    for(int j=0;j<20;j++) s+=T1s[a][j]*W[j*18+c2];
    A[a][c2]=s;
  }
  __syncthreads();
  for(int idx=tid; idx<324; idx+=64){
    int i=idx/18, j=idx-i*18;
    if(i<j){ float v=0.5f*(A[i][j]+A[j][i]); A[i][j]=v; A[j][i]=v; }
  }
  __syncthreads();
  jacobi18(A,V,cc,bb,pr,tid);
  __syncthreads();
  if(tid<18) bb[tid]=logf(fmaxf(A[tid][tid],1e-12f));
  __syncthreads();
  for(int idx=tid; idx<324; idx+=64){
    int i=idx/18, k=idx-i*18;
    T1s[i][k]=V[i][k]*bb[k];
  }
  __syncthreads();
  float* ob = ws + ((m==0)?OFF_LQ:((m==1)?OFF_LK:OFF_LV)) + ((size_t)b*3+p)*324;
  for(int idx=tid; idx<324; idx+=64){
    int i=idx/18, j=idx-i*18;
    float s=0.f;
    #pragma unroll
    for(int k=0;k<18;k++) s+=T1s[i][k]*V[j][k];
    ob[idx]=s;
  }
}

// energies, softmax over K-index, mean_log = sum_i prob * logV
__global__ __launch_bounds__(64) void k_att(float* __restrict__ ws){
  __shared__ float lq[972], lk[972];
  __shared__ float e[9];
  __shared__ float prob[3][3];
  int b=blockIdx.x, tid=threadIdx.x;
  const float* LQ=ws+OFF_LQ+(size_t)b*972;
  const float* LK=ws+OFF_LK+(size_t)b*972;
  for(int idx=tid; idx<972; idx+=64){ lq[idx]=LQ[idx]; lk[idx]=LK[idx]; }
  __syncthreads();
  if(tid<9){
    int i=tid/3, p=tid-i*3;
    const float* ki=lk+i*324; const float* qp=lq+p*324;
    float s=0.f;
    for(int el=0;el<324;el++){ float d=ki[el]-qp[el]; s+=d*d; }
    e[tid]=s;
  }
  __syncthreads();
  if(tid<3){
    float f0=1.f/(1.f+log1pf(e[0+tid]));
    float f1=1.f/(1.f+log1pf(e[3+tid]));
    float f2=1.f/(1.f+log1pf(e[6+tid]));
    float mx=fmaxf(f0,fmaxf(f1,f2));
    float x0=expf(f0-mx), x1=expf(f1-mx), x2=expf(f2-mx);
    float inv=1.f/(x0+x1+x2);
    prob[tid][0]=x0*inv; prob[tid][1]=x1*inv; prob[tid][2]=x2*inv;
  }
  __syncthreads();
  const float* LV=ws+OFF_LV+(size_t)b*972;
  float* ML=ws+OFF_ML+(size_t)b*972;
  for(int idx=tid; idx<972; idx+=64){
    int p=idx/324, el=idx-p*324;
    ML[idx]=prob[p][0]*LV[el]+prob[p][1]*LV[324+el]+prob[p][2]*LV[648+el];
  }
}

// eigh(mean_log); tang = U max(s, ln 1e-4) U^T (= logm(rectify(expm()))); triu feat
__global__ __launch_bounds__(64) void k_eigh2(float* __restrict__ ws){
  __shared__ float A[18][19];
  __shared__ float V[18][19];
  __shared__ float W2[18][19];
  __shared__ float cc[18], bb[18];
  __shared__ int pr[18];
  int blk=blockIdx.x, tid=threadIdx.x;
  int b=blk/3, p=blk-b*3;
  const float* ML=ws+OFF_ML+((size_t)b*3+p)*324;
  for(int idx=tid; idx<324; idx+=64){ int i=idx/18,j=idx-i*18; A[i][j]=ML[idx]; }
  __syncthreads();
  for(int idx=tid; idx<324; idx+=64){
    int i=idx/18, j=idx-i*18;
    if(i<j){ float v=0.5f*(A[i][j]+A[j][i]); A[i][j]=v; A[j][i]=v; }
  }
  __syncthreads();
  jacobi18(A,V,cc,bb,pr,tid);
  __syncthreads();
  if(tid<18) bb[tid]=fmaxf(A[tid][tid], -9.2103404f);
  __syncthreads();
  for(int idx=tid; idx<324; idx+=64){ int i=idx/18,k=idx-i*18; W2[i][k]=V[i][k]*bb[k]; }
  __syncthreads();
  float* fb = ws + OFF_FEAT + (size_t)b*513 + p*171;
  for(int idx=tid; idx<171; idx+=64){
    int r=idx, i=0;
    while(true){ int c=18-i; if(r<c) break; r-=c; i++; }
    int j=i+r;
    float s=0.f;
    #pragma unroll
    for(int k=0;k<18;k++) s+=W2[i][k]*V[j][k];
    fb[idx]=s;
  }
}

__global__ __launch_bounds__(256) void k_lin(const float* __restrict__ lw,
                                             const float* __restrict__ lb,
                                             const float* __restrict__ ws,
                                             float* __restrict__ out){
  int t=blockIdx.x*256+threadIdx.x;
  if(t>=B_*4) return;
  int b=t>>2, j=t&3;
  const float* f=ws+OFF_FEAT+(size_t)b*513;
  const float* w=lw+j*513;
  float s=lb[j];
  for(int k=0;k<513;k++) s+=f[k]*w[k];
  out[t]=s;
}

extern "C" void kernel_launch(void* const* d_in, const int* in_sizes, int n_in,
                              void* d_out, int out_size, void* d_ws, size_t ws_size,
                              hipStream_t stream){
  const float* x  =(const float*)d_in[0];
  const float* w1 =(const float*)d_in[1];
  const float* cb1=(const float*)d_in[2];
  const float* g1 =(const float*)d_in[3];
  const float* bb1=(const float*)d_in[4];
  const float* w2 =(const float*)d_in[5];
  // d_in[6] conv2_b, d_in[8] bn2_b: provably cancel (centering / variance invariance)
  const float* g2 =(const float*)d_in[7];
  const float* Wq =(const float*)d_in[9];
  const float* Wk =(const float*)d_in[10];
  const float* Wv =(const float*)d_in[11];
  const float* lw =(const float*)d_in[12];
  const float* lb =(const float*)d_in[13];
  float* ws=(float*)d_ws;
  float* out=(float*)d_out;

  k_zero<<<1,256,0,stream>>>(ws);
  k_moment<<<B_,256,0,stream>>>(x,ws);
  k_fin1<<<1,64,0,stream>>>(w1,cb1,g1,bb1,ws);
  k_conv2cov<<<B_,256,0,stream>>>(x,w1,w2,ws);
  k_fin2<<<1,64,0,stream>>>(g2,ws);
  k_eighQKV<<<B_*9,64,0,stream>>>(Wq,Wk,Wv,ws);
  k_att<<<B_,64,0,stream>>>(ws);
  k_eigh2<<<B_*3,64,0,stream>>>(ws);
  k_lin<<<(B_*4+255)/256,256,0,stream>>>(lw,lb,ws,out);
}

// Round 2
// 1591.658 us; speedup vs baseline: 1.4886x; 1.4886x over previous
//
#include <hip/hip_runtime.h>
#include <cmath>

#define B_ 1024
#define CIN_ 22
#define T1_ 438
#define COUT_ 20
#define T2_ 439

// ws float offsets (total ~23 MB required)
#define OFF_S 0
#define OFF_M 32
#define OFF_A1 520
#define OFF_E1 544
#define OFF_SUM2 576
#define OFF_SSQ2 608
#define OFF_A2 640
#define OFF_ACC_END 704
#define OFF_C 1024
#define OFF_LQ (OFF_C + B_*3*400)
#define OFF_LK (OFF_LQ + B_*3*324)
#define OFF_LV (OFF_LK + B_*3*324)
#define OFF_ML (OFF_LV + B_*3*324)
#define OFF_FEAT (OFF_ML + B_*3*324)
#define WS_FLOATS (OFF_FEAT + B_*513)

__global__ __launch_bounds__(256) void k_zero(float* ws){
  for(int i=threadIdx.x; i<OFF_ACC_END; i+=256) ws[i]=0.f;
}

// bn1 stats via second-moment matrix of x: S[22], M[22][22] (triu)
__global__ __launch_bounds__(256) void k_moment(const float* __restrict__ x, float* __restrict__ ws){
  __shared__ float xs[CIN_*T1_];
  int b=blockIdx.x;
  const float* xb = x + (size_t)b*CIN_*T1_;
  for(int i=threadIdx.x;i<CIN_*T1_;i+=256) xs[i]=xb[i];
  __syncthreads();
  for(int tgt=threadIdx.x; tgt<275; tgt+=256){
    if(tgt<253){
      int r=tgt, i=0;
      while(true){ int c=CIN_-i; if(r<c) break; r-=c; i++; }
      int j=i+r;
      const float* ri=xs+i*T1_; const float* rj=xs+j*T1_;
      float acc=0.f;
      for(int t=0;t<T1_;t++) acc += ri[t]*rj[t];
      atomicAdd(&ws[OFF_M + i*CIN_ + j], acc);
    } else {
      int c=tgt-253;
      const float* rc=xs+c*T1_;
      float acc=0.f;
      for(int t=0;t<T1_;t++) acc += rc[t];
      atomicAdd(&ws[OFF_S + c], acc);
    }
  }
}

__global__ void k_fin1(const float* __restrict__ w1, const float* __restrict__ cb1,
                       const float* __restrict__ g1, const float* __restrict__ bb1,
                       float* __restrict__ ws){
  int c=threadIdx.x;
  if(c>=CIN_) return;
  const double N = (double)B_*T1_;
  double wS=0.0, wMw=0.0;
  for(int h=0;h<CIN_;h++) wS += (double)w1[c*CIN_+h]*(double)ws[OFF_S+h];
  for(int h=0;h<CIN_;h++){
    for(int h2=0;h2<CIN_;h2++){
      int i=h<h2?h:h2, j=h<h2?h2:h;
      wMw += (double)w1[c*CIN_+h]*(double)w1[c*CIN_+h2]*(double)ws[OFF_M+i*CIN_+j];
    }
  }
  double bc=cb1[c];
  double mean=wS/N+bc;
  double ex2=(wMw+2.0*bc*wS)/N+bc*bc;
  double var=ex2-mean*mean;
  double a1=(double)g1[c]/sqrt(var+1e-5);
  double d1=(double)bb1[c]-mean*a1;
  ws[OFF_A1+c]=(float)a1;            // y = a1*conv1 + e1
  ws[OFF_E1+c]=(float)(a1*bc+d1);
}

// per-batch: y = bn1(conv1(x)); h2 = conv2(y); raw patch covariances + bn2 sums
__global__ __launch_bounds__(256) void k_conv2cov(const float* __restrict__ x,
                                                  const float* __restrict__ w1,
                                                  const float* __restrict__ w2,
                                                  float* __restrict__ ws){
  __shared__ float yw[CIN_][160];
  __shared__ float h2w[COUT_][148];
  __shared__ float w2s[COUT_*CIN_*12];
  __shared__ float w1s[CIN_*CIN_];
  __shared__ float a1s[CIN_], e1s[CIN_];
  __shared__ float acc1[COUT_], acc2[COUT_], pmu[COUT_];
  int b=blockIdx.x, tid=threadIdx.x;
  for(int i=tid;i<COUT_*CIN_*12;i+=256) w2s[i]=w2[i];
  for(int i=tid;i<CIN_*CIN_;i+=256) w1s[i]=w1[i];
  if(tid<CIN_){ a1s[tid]=ws[OFF_A1+tid]; e1s[tid]=ws[OFF_E1+tid]; }
  if(tid<COUT_){ acc1[tid]=0.f; acc2[tid]=0.f; }
  __syncthreads();
  for(int p=0;p<3;p++){
    int off = (p==0)?0:((p==1)?147:293);
    int L = (p==0)?147:146;
    int ycols = L+11;
    int ybase = off-6;
    for(int idx=tid; idx<CIN_*ycols; idx+=256){
      int c=idx/ycols, tt=idx-c*ycols, gt=ybase+tt;
      float v=0.f;
      if(gt>=0 && gt<T1_){
        const float* xb=x+(size_t)b*CIN_*T1_+gt;
        float s=0.f;
        for(int h=0;h<CIN_;h++) s += w1s[c*CIN_+h]*xb[(size_t)h*T1_];
        v = a1s[c]*s + e1s[c];
      }
      yw[c][tt]=v;
    }
    __syncthreads();
    for(int idx=tid; idx<COUT_*L; idx+=256){
      int o=idx/L, tt=idx-o*L;
      float s=0.f;
      for(int i=0;i<CIN_;i++){
        const float* wo=&w2s[(o*CIN_+i)*12];
        const float* yr=&yw[i][tt];
        #pragma unroll
        for(int k=0;k<12;k++) s += wo[k]*yr[k];
      }
      h2w[o][tt]=s;
    }
    __syncthreads();
    if(tid<COUT_){
      float s1=0.f,s2=0.f;
      for(int t=0;t<L;t++){ float v=h2w[tid][t]; s1+=v; s2+=v*v; }
      acc1[tid]+=s1; acc2[tid]+=s2; pmu[tid]=s1/(float)L;
    }
    __syncthreads();
    float* Cb = ws + OFF_C + ((size_t)b*3+p)*400;
    for(int pp=tid; pp<210; pp+=256){
      int r=pp, i=0;
      while(true){ int c=COUT_-i; if(r<c) break; r-=c; i++; }
      int j=i+r;
      float s=0.f;
      for(int t=0;t<L;t++) s += h2w[i][t]*h2w[j][t];
      s -= (float)L*pmu[i]*pmu[j];
      Cb[i*COUT_+j]=s;
      Cb[j*COUT_+i]=s;
    }
    __syncthreads();
  }
  if(tid<COUT_){
    atomicAdd(&ws[OFF_SUM2+tid], acc1[tid]);
    atomicAdd(&ws[OFF_SSQ2+tid], acc2[tid]);
  }
}

__global__ void k_fin2(const float* __restrict__ g2, float* __restrict__ ws){
  int c=threadIdx.x; if(c>=COUT_) return;
  const double N=(double)B_*T2_;
  double m=ws[OFF_SUM2+c]/N;
  double v=ws[OFF_SSQ2+c]/N - m*m;
  ws[OFF_A2+c]=(float)((double)g2[c]/sqrt(v+1e-5));
}

// ---------------------------------------------------------------------------
// One-sided Jacobi eigensolver for SPD 18x18, fully register-resident.
// 16-lane group per matrix, 4 matrices per wave. Lane l holds rows l and l+16
// of M (=A, transformed by right-rotations) and V (accumulated rotations).
// Column dots via shfl_xor butterflies (masks 1,2,4,8 stay inside 16-group).
// Round-robin schedule made index-invariant by cyclic register renaming:
// pairs are always (0,17),(1,16),...,(8,9); after each step cols 0..16 shift.
// ---------------------------------------------------------------------------
__device__ __forceinline__ void onesided18(float M0[18], float M1[18],
                                           float V0[18], float V1[18],
                                           float dg[18], int maxsweep){
  for(int sweep=0; sweep<maxsweep; sweep++){
    // refresh column norms^2 (kills drift of the incremental updates)
    #pragma unroll
    for(int k=0;k<18;k++){
      float v = M0[k]*M0[k] + M1[k]*M1[k];
      v += __shfl_xor(v,1); v += __shfl_xor(v,2);
      v += __shfl_xor(v,4); v += __shfl_xor(v,8);
      dg[k]=v;
    }
    float smax=0.f;
    for(int r=0;r<17;r++){
      #pragma unroll
      for(int T=0;T<9;T++){
        const int p=T, q=(T==0)?17:(17-T);
        // apq = <col p, col q>, identical (bitwise) in all lanes of the group
        float v = M0[p]*M0[q] + M1[p]*M1[q];
        v += __shfl_xor(v,1); v += __shfl_xor(v,2);
        v += __shfl_xor(v,4); v += __shfl_xor(v,8);
        float app=dg[p], aqq=dg[q];
        float tau = __fdividef(aqq-app, 2.f*v);
        float tt  = __fdividef(copysignf(1.f,tau), fabsf(tau)+sqrtf(1.f+tau*tau));
        float c   = rsqrtf(1.f+tt*tt);
        float s   = tt*c;
        bool  z   = (v==0.f);
        tt = z?0.f:tt; c = z?1.f:c; s = z?0.f:s;
        dg[p]=app-tt*v; dg[q]=aqq+tt*v;
        smax=fmaxf(smax,fabsf(s));
        float x,y;
        x=M0[p]; y=M0[q]; M0[p]=c*x-s*y; M0[q]=s*x+c*y;
        x=M1[p]; y=M1[q]; M1[p]=c*x-s*y; M1[q]=s*x+c*y;
        x=V0[p]; y=V0[q]; V0[p]=c*x-s*y; V0[q]=s*x+c*y;
        x=V1[p]; y=V1[q]; V1[p]=c*x-s*y; V1[q]=s*x+c*y;
      }
      // cyclic rename of columns 0..16 (col 17 is the fixed tournament seat)
      {
        float t0=M0[0],t1=M1[0],t2=V0[0],t3=V1[0],t4=dg[0];
        #pragma unroll
        for(int k=0;k<16;k++){
          M0[k]=M0[k+1]; M1[k]=M1[k+1]; V0[k]=V0[k+1]; V1[k]=V1[k+1]; dg[k]=dg[k+1];
        }
        M0[16]=t0; M1[16]=t1; V0[16]=t2; V1[16]=t3; dg[16]=t4;
      }
    }
    if(__all(smax < 2e-6f)) break;
  }
  // final exact column norms^2
  #pragma unroll
  for(int k=0;k<18;k++){
    float v = M0[k]*M0[k] + M1[k]*M1[k];
    v += __shfl_xor(v,1); v += __shfl_xor(v,2);
    v += __shfl_xor(v,4); v += __shfl_xor(v,8);
    dg[k]=v;
  }
}

// out = V * diag(fk) * V^T, written (full 18x18) into AbG (this group's LDS tile)
__device__ __forceinline__ void spectral_out(const float V0[18], const float V1[18],
                                             const float fk[18], float* AbG, int l){
  float w0[18], w1[18];
  #pragma unroll
  for(int k=0;k<18;k++){ w0[k]=V0[k]*fk[k]; w1[k]=V1[k]*fk[k]; }
  int base = threadIdx.x & 48;
  #pragma unroll
  for(int j=0;j<18;j++){
    float o0=0.f, o1=0.f;
    #pragma unroll
    for(int k=0;k<18;k++){
      float vj = __shfl((j<16)?V0[k]:V1[k], base+(j&15));
      o0 += w0[k]*vj;
      o1 += w1[k]*vj;
    }
    AbG[l*18+j]=o0;
    if(l<2) AbG[(l+16)*18+j]=o1;
  }
}

// scale C by a2, trace-normalize, +1e-5 I, congruence with W, logm -> store.
// One wave per block; 4 matrices per block (same m, consecutive (b,p)).
__global__ __launch_bounds__(64,4) void k_eighQKV(const float* __restrict__ Wq,
                                                  const float* __restrict__ Wk,
                                                  const float* __restrict__ Wv,
                                                  float* __restrict__ ws){
  __shared__ float Wl[360];
  __shared__ float Cm[420];   // 20x21
  __shared__ float Tt[378];   // 18x21
  __shared__ float Ab[1296];  // 4 x 324
  __shared__ float a2s[20];
  int wid=blockIdx.x, tid=threadIdx.x;
  int m = wid/768;
  int bp4 = (wid - m*768)*4;
  const float* W = (m==0)?Wq:((m==1)?Wk:Wv);
  for(int i=tid;i<360;i+=64) Wl[i]=W[i];
  if(tid<20) a2s[tid]=ws[OFF_A2+tid];
  __syncthreads();
  // prep: A_g = W^T C'_g W into Ab[g]
  for(int g=0; g<4; g++){
    const float* Cb = ws + OFF_C + (size_t)(bp4+g)*400;
    for(int idx=tid; idx<400; idx+=64){
      int i=idx/20, j=idx-i*20;
      Cm[i*21+j]=Cb[idx]*a2s[i]*a2s[j];
    }
    __syncthreads();
    float tr=0.f;
    #pragma unroll
    for(int i=0;i<20;i++) tr += Cm[i*21+i];
    float invtr = 1.f/tr;
    for(int idx=tid; idx<360; idx+=64){
      int a=idx/20, j=idx-a*20;
      float s=0.f;
      for(int i=0;i<20;i++){
        float cij = Cm[i*21+j]*invtr + ((i==j)?1e-5f:0.f);
        s += Wl[i*18+a]*cij;
      }
      Tt[a*21+j]=s;
    }
    __syncthreads();
    for(int idx=tid; idx<324; idx+=64){
      int a=idx/18, c=idx-a*18;
      float s=0.f;
      for(int j=0;j<20;j++) s += Tt[a*21+j]*Wl[j*18+c];
      Ab[g*324+idx]=s;
    }
    __syncthreads();
  }
  // register-resident one-sided Jacobi (4 matrices in parallel across the wave)
  int l = tid & 15, g = tid >> 4;
  float* AbG = &Ab[g*324];
  float M0[18],M1[18],V0[18],V1[18],dg[18];
  #pragma unroll
  for(int k=0;k<18;k++){
    M0[k] = 0.5f*(AbG[l*18+k] + AbG[k*18+l]);                       // row l, symmetrized
    M1[k] = (l<2) ? 0.5f*(AbG[(l+16)*18+k] + AbG[k*18+l+16]) : 0.f; // row l+16
    V0[k] = (k==l)?1.f:0.f;
    V1[k] = (l<2 && k==l+16)?1.f:0.f;
  }
  onesided18(M0,M1,V0,V1,dg,11);
  float fk[18];
  #pragma unroll
  for(int k=0;k<18;k++) fk[k] = 0.5f*logf(fmaxf(dg[k],1e-24f));  // log(lambda)
  spectral_out(V0,V1,fk,AbG,l);
  __syncthreads();
  float* ob = ws + ((m==0)?OFF_LQ:((m==1)?OFF_LK:OFF_LV)) + (size_t)bp4*324;
  for(int idx=tid; idx<1296; idx+=64) ob[idx]=Ab[idx];
}

// energies, softmax over K-index, mean_log = sum_i prob * logV
__global__ __launch_bounds__(64) void k_att(float* __restrict__ ws){
  __shared__ float lq[972], lk[972];
  __shared__ float e[9];
  __shared__ float prob[3][3];
  int b=blockIdx.x, tid=threadIdx.x;
  const float* LQ=ws+OFF_LQ+(size_t)b*972;
  const float* LK=ws+OFF_LK+(size_t)b*972;
  for(int idx=tid; idx<972; idx+=64){ lq[idx]=LQ[idx]; lk[idx]=LK[idx]; }
  __syncthreads();
  if(tid<9){
    int i=tid/3, p=tid-i*3;
    const float* ki=lk+i*324; const float* qp=lq+p*324;
    float s=0.f;
    for(int el=0;el<324;el++){ float d=ki[el]-qp[el]; s+=d*d; }
    e[tid]=s;
  }
  __syncthreads();
  if(tid<3){
    float f0=1.f/(1.f+log1pf(e[0+tid]));
    float f1=1.f/(1.f+log1pf(e[3+tid]));
    float f2=1.f/(1.f+log1pf(e[6+tid]));
    float mx=fmaxf(f0,fmaxf(f1,f2));
    float x0=expf(f0-mx), x1=expf(f1-mx), x2=expf(f2-mx);
    float inv=1.f/(x0+x1+x2);
    prob[tid][0]=x0*inv; prob[tid][1]=x1*inv; prob[tid][2]=x2*inv;
  }
  __syncthreads();
  const float* LV=ws+OFF_LV+(size_t)b*972;
  float* ML=ws+OFF_ML+(size_t)b*972;
  for(int idx=tid; idx<972; idx+=64){
    int p=idx/324, el=idx-p*324;
    ML[idx]=prob[p][0]*LV[el]+prob[p][1]*LV[324+el]+prob[p][2]*LV[648+el];
  }
}

// eigh(mean_log + 12I) via one-sided SPD Jacobi (spectrum of mean_log is in
// [ln 1e-5, 1e-5] so the +12 shift is provably SPD); tang-eigvals = max(s,-9.21);
// triu features.
__global__ __launch_bounds__(64,4) void k_eigh2(float* __restrict__ ws){
  __shared__ float Ab[1296];
  int wid=blockIdx.x, tid=threadIdx.x;
  const float* ML = ws + OFF_ML + (size_t)wid*1296;
  for(int idx=tid; idx<1296; idx+=64) Ab[idx]=ML[idx];
  __syncthreads();
  int l = tid & 15, g = tid >> 4;
  float* AbG = &Ab[g*324];
  float M0[18],M1[18],V0[18],V1[18],dg[18];
  #pragma unroll
  for(int k=0;k<18;k++){
    float a0 = 0.5f*(AbG[l*18+k] + AbG[k*18+l]);
    if(k==l) a0 += 12.f;
    M0[k]=a0;
    float a1 = (l<2) ? 0.5f*(AbG[(l+16)*18+k] + AbG[k*18+l+16]) : 0.f;
    if(l<2 && k==l+16) a1 += 12.f;
    M1[k]=a1;
    V0[k] = (k==l)?1.f:0.f;
    V1[k] = (l<2 && k==l+16)?1.f:0.f;
  }
  onesided18(M0,M1,V0,V1,dg,9);
  float fk[18];
  #pragma unroll
  for(int k=0;k<18;k++) fk[k] = fmaxf(sqrtf(dg[k])-12.f, -9.2103404f);
  spectral_out(V0,V1,fk,AbG,l);
  __syncthreads();
  // triu extract -> feat (bp = wid*4+g2, feat offset bp*171, contiguous 684)
  float* fb = ws + OFF_FEAT + (size_t)wid*684;
  for(int idx=tid; idx<684; idx+=64){
    int g2=idx/171, t=idx-g2*171;
    int i=0, r=t;
    while(true){ int c=18-i; if(r<c) break; r-=c; i++; }
    int j=i+r;
    fb[idx]=Ab[g2*324 + i*18 + j];
  }
}

__global__ __launch_bounds__(256) void k_lin(const float* __restrict__ lw,
                                             const float* __restrict__ lb,
                                             const float* __restrict__ ws,
                                             float* __restrict__ out){
  int t=blockIdx.x*256+threadIdx.x;
  if(t>=B_*4) return;
  int b=t>>2, j=t&3;
  const float* f=ws+OFF_FEAT+(size_t)b*513;
  const float* w=lw+j*513;
  float s=lb[j];
  for(int k=0;k<513;k++) s+=f[k]*w[k];
  out[t]=s;
}

extern "C" void kernel_launch(void* const* d_in, const int* in_sizes, int n_in,
                              void* d_out, int out_size, void* d_ws, size_t ws_size,
                              hipStream_t stream){
  const float* x  =(const float*)d_in[0];
  const float* w1 =(const float*)d_in[1];
  const float* cb1=(const float*)d_in[2];
  const float* g1 =(const float*)d_in[3];
  const float* bb1=(const float*)d_in[4];
  const float* w2 =(const float*)d_in[5];
  // d_in[6] conv2_b, d_in[8] bn2_b: provably cancel (centering / variance invariance)
  const float* g2 =(const float*)d_in[7];
  const float* Wq =(const float*)d_in[9];
  const float* Wk =(const float*)d_in[10];
  const float* Wv =(const float*)d_in[11];
  const float* lw =(const float*)d_in[12];
  const float* lb =(const float*)d_in[13];
  float* ws=(float*)d_ws;
  float* out=(float*)d_out;

  k_zero<<<1,256,0,stream>>>(ws);
  k_moment<<<B_,256,0,stream>>>(x,ws);
  k_fin1<<<1,64,0,stream>>>(w1,cb1,g1,bb1,ws);
  k_conv2cov<<<B_,256,0,stream>>>(x,w1,w2,ws);
  k_fin2<<<1,64,0,stream>>>(g2,ws);
  k_eighQKV<<<2304,64,0,stream>>>(Wq,Wk,Wv,ws);
  k_att<<<B_,64,0,stream>>>(ws);
  k_eigh2<<<768,64,0,stream>>>(ws);
  k_lin<<<(B_*4+255)/256,256,0,stream>>>(lw,lb,ws,out);
}

// Round 3
// 1363.692 us; speedup vs baseline: 1.7375x; 1.1672x over previous
//
#include <hip/hip_runtime.h>
#include <cmath>

#define B_ 1024
#define CIN_ 22
#define T1_ 438
#define COUT_ 20
#define T2_ 439

// ws float offsets (total ~23 MB required)
#define OFF_S 0
#define OFF_M 32
#define OFF_A1 520
#define OFF_E1 544
#define OFF_SUM2 576
#define OFF_SSQ2 608
#define OFF_A2 640
#define OFF_ACC_END 704
#define OFF_C 1024
#define OFF_LQ (OFF_C + B_*3*400)
#define OFF_LK (OFF_LQ + B_*3*324)
#define OFF_LV (OFF_LK + B_*3*324)
#define OFF_ML (OFF_LV + B_*3*324)
#define OFF_FEAT (OFF_ML + B_*3*324)
#define WS_FLOATS (OFF_FEAT + B_*513)

__global__ __launch_bounds__(256) void k_zero(float* ws){
  for(int i=threadIdx.x; i<OFF_ACC_END; i+=256) ws[i]=0.f;
}

// bn1 stats via second-moment matrix of x: S[22], M[22][22] (triu)
__global__ __launch_bounds__(256) void k_moment(const float* __restrict__ x, float* __restrict__ ws){
  __shared__ float xs[CIN_*T1_];
  int b=blockIdx.x;
  const float* xb = x + (size_t)b*CIN_*T1_;
  for(int i=threadIdx.x;i<CIN_*T1_;i+=256) xs[i]=xb[i];
  __syncthreads();
  for(int tgt=threadIdx.x; tgt<275; tgt+=256){
    if(tgt<253){
      int r=tgt, i=0;
      while(true){ int c=CIN_-i; if(r<c) break; r-=c; i++; }
      int j=i+r;
      const float* ri=xs+i*T1_; const float* rj=xs+j*T1_;
      float acc=0.f;
      for(int t=0;t<T1_;t++) acc += ri[t]*rj[t];
      atomicAdd(&ws[OFF_M + i*CIN_ + j], acc);
    } else {
      int c=tgt-253;
      const float* rc=xs+c*T1_;
      float acc=0.f;
      for(int t=0;t<T1_;t++) acc += rc[t];
      atomicAdd(&ws[OFF_S + c], acc);
    }
  }
}

__global__ void k_fin1(const float* __restrict__ w1, const float* __restrict__ cb1,
                       const float* __restrict__ g1, const float* __restrict__ bb1,
                       float* __restrict__ ws){
  int c=threadIdx.x;
  if(c>=CIN_) return;
  const double N = (double)B_*T1_;
  double wS=0.0, wMw=0.0;
  for(int h=0;h<CIN_;h++) wS += (double)w1[c*CIN_+h]*(double)ws[OFF_S+h];
  for(int h=0;h<CIN_;h++){
    for(int h2=0;h2<CIN_;h2++){
      int i=h<h2?h:h2, j=h<h2?h2:h;
      wMw += (double)w1[c*CIN_+h]*(double)w1[c*CIN_+h2]*(double)ws[OFF_M+i*CIN_+j];
    }
  }
  double bc=cb1[c];
  double mean=wS/N+bc;
  double ex2=(wMw+2.0*bc*wS)/N+bc*bc;
  double var=ex2-mean*mean;
  double a1=(double)g1[c]/sqrt(var+1e-5);
  double d1=(double)bb1[c]-mean*a1;
  ws[OFF_A1+c]=(float)a1;            // y = a1*conv1 + e1
  ws[OFF_E1+c]=(float)(a1*bc+d1);
}

// per-batch: y = bn1(conv1(x)); h2 = conv2(y); raw patch covariances + bn2 sums
__global__ __launch_bounds__(256) void k_conv2cov(const float* __restrict__ x,
                                                  const float* __restrict__ w1,
                                                  const float* __restrict__ w2,
                                                  float* __restrict__ ws){
  __shared__ float yw[CIN_][160];
  __shared__ float h2w[COUT_][148];
  __shared__ float w2s[COUT_*CIN_*12];
  __shared__ float w1s[CIN_*CIN_];
  __shared__ float a1s[CIN_], e1s[CIN_];
  __shared__ float acc1[COUT_], acc2[COUT_], pmu[COUT_];
  int b=blockIdx.x, tid=threadIdx.x;
  for(int i=tid;i<COUT_*CIN_*12;i+=256) w2s[i]=w2[i];
  for(int i=tid;i<CIN_*CIN_;i+=256) w1s[i]=w1[i];
  if(tid<CIN_){ a1s[tid]=ws[OFF_A1+tid]; e1s[tid]=ws[OFF_E1+tid]; }
  if(tid<COUT_){ acc1[tid]=0.f; acc2[tid]=0.f; }
  __syncthreads();
  for(int p=0;p<3;p++){
    int off = (p==0)?0:((p==1)?147:293);
    int L = (p==0)?147:146;
    int ycols = L+11;
    int ybase = off-6;
    for(int idx=tid; idx<CIN_*ycols; idx+=256){
      int c=idx/ycols, tt=idx-c*ycols, gt=ybase+tt;
      float v=0.f;
      if(gt>=0 && gt<T1_){
        const float* xb=x+(size_t)b*CIN_*T1_+gt;
        float s=0.f;
        for(int h=0;h<CIN_;h++) s += w1s[c*CIN_+h]*xb[(size_t)h*T1_];
        v = a1s[c]*s + e1s[c];
      }
      yw[c][tt]=v;
    }
    __syncthreads();
    for(int idx=tid; idx<COUT_*L; idx+=256){
      int o=idx/L, tt=idx-o*L;
      float s=0.f;
      for(int i=0;i<CIN_;i++){
        const float* wo=&w2s[(o*CIN_+i)*12];
        const float* yr=&yw[i][tt];
        #pragma unroll
        for(int k=0;k<12;k++) s += wo[k]*yr[k];
      }
      h2w[o][tt]=s;
    }
    __syncthreads();
    if(tid<COUT_){
      float s1=0.f,s2=0.f;
      for(int t=0;t<L;t++){ float v=h2w[tid][t]; s1+=v; s2+=v*v; }
      acc1[tid]+=s1; acc2[tid]+=s2; pmu[tid]=s1/(float)L;
    }
    __syncthreads();
    float* Cb = ws + OFF_C + ((size_t)b*3+p)*400;
    for(int pp=tid; pp<210; pp+=256){
      int r=pp, i=0;
      while(true){ int c=COUT_-i; if(r<c) break; r-=c; i++; }
      int j=i+r;
      float s=0.f;
      for(int t=0;t<L;t++) s += h2w[i][t]*h2w[j][t];
      s -= (float)L*pmu[i]*pmu[j];
      Cb[i*COUT_+j]=s;
      Cb[j*COUT_+i]=s;
    }
    __syncthreads();
  }
  if(tid<COUT_){
    atomicAdd(&ws[OFF_SUM2+tid], acc1[tid]);
    atomicAdd(&ws[OFF_SSQ2+tid], acc2[tid]);
  }
}

__global__ void k_fin2(const float* __restrict__ g2, float* __restrict__ ws){
  int c=threadIdx.x; if(c>=COUT_) return;
  const double N=(double)B_*T2_;
  double m=ws[OFF_SUM2+c]/N;
  double v=ws[OFF_SSQ2+c]/N - m*m;
  ws[OFF_A2+c]=(float)((double)g2[c]/sqrt(v+1e-5));
}

// ---------------------------------------------------------------------------
// One-sided Jacobi eigensolver for SPD 18x18, fully register-resident.
// 16-lane group per matrix, 4 matrices per wave. Lane l holds rows l and l+16
// of M (=A, transformed by right-rotations) and V (accumulated rotations).
// Column dots via shfl_xor butterflies (masks 1,2,4,8 stay inside 16-group).
// Round-robin schedule made index-invariant by cyclic register renaming:
// pairs are always (0,17),(1,16),...,(8,9); after each step cols 0..16 shift.
// NOTE: no min-waves in __launch_bounds__ — the 90+ float per-lane state must
// stay in VGPRs (a 4-waves/EU hint capped VGPRs at 64 and spilled 262 MB to
// scratch per dispatch in R1).
// ---------------------------------------------------------------------------
__device__ __forceinline__ void onesided18(float M0[18], float M1[18],
                                           float V0[18], float V1[18],
                                           float dg[18], int maxsweep){
  for(int sweep=0; sweep<maxsweep; sweep++){
    // refresh column norms^2 (kills drift of the incremental updates)
    #pragma unroll
    for(int k=0;k<18;k++){
      float v = M0[k]*M0[k] + M1[k]*M1[k];
      v += __shfl_xor(v,1); v += __shfl_xor(v,2);
      v += __shfl_xor(v,4); v += __shfl_xor(v,8);
      dg[k]=v;
    }
    float smax=0.f;
    for(int r=0;r<17;r++){
      #pragma unroll
      for(int T=0;T<9;T++){
        const int p=T, q=(T==0)?17:(17-T);
        // apq = <col p, col q>, identical (bitwise) in all lanes of the group
        float v = M0[p]*M0[q] + M1[p]*M1[q];
        v += __shfl_xor(v,1); v += __shfl_xor(v,2);
        v += __shfl_xor(v,4); v += __shfl_xor(v,8);
        float app=dg[p], aqq=dg[q];
        float tau = __fdividef(aqq-app, 2.f*v);
        float tt  = __fdividef(copysignf(1.f,tau), fabsf(tau)+sqrtf(1.f+tau*tau));
        float c   = rsqrtf(1.f+tt*tt);
        float s   = tt*c;
        bool  z   = (v==0.f);
        tt = z?0.f:tt; c = z?1.f:c; s = z?0.f:s;
        dg[p]=app-tt*v; dg[q]=aqq+tt*v;
        smax=fmaxf(smax,fabsf(s));
        float x,y;
        x=M0[p]; y=M0[q]; M0[p]=c*x-s*y; M0[q]=s*x+c*y;
        x=M1[p]; y=M1[q]; M1[p]=c*x-s*y; M1[q]=s*x+c*y;
        x=V0[p]; y=V0[q]; V0[p]=c*x-s*y; V0[q]=s*x+c*y;
        x=V1[p]; y=V1[q]; V1[p]=c*x-s*y; V1[q]=s*x+c*y;
      }
      // cyclic rename of columns 0..16 (col 17 is the fixed tournament seat)
      {
        float t0=M0[0],t1=M1[0],t2=V0[0],t3=V1[0],t4=dg[0];
        #pragma unroll
        for(int k=0;k<16;k++){
          M0[k]=M0[k+1]; M1[k]=M1[k+1]; V0[k]=V0[k+1]; V1[k]=V1[k+1]; dg[k]=dg[k+1];
        }
        M0[16]=t0; M1[16]=t1; V0[16]=t2; V1[16]=t3; dg[16]=t4;
      }
    }
    if(__all(smax < 1e-5f)) break;
  }
  // final exact column norms^2
  #pragma unroll
  for(int k=0;k<18;k++){
    float v = M0[k]*M0[k] + M1[k]*M1[k];
    v += __shfl_xor(v,1); v += __shfl_xor(v,2);
    v += __shfl_xor(v,4); v += __shfl_xor(v,8);
    dg[k]=v;
  }
}

// out = V * diag(fk) * V^T, written (full 18x18) into AbG (this group's LDS
// tile). Destroys M0/M1 (dead after the solve) to avoid new registers at peak.
__device__ __forceinline__ void spectral_out(float M0[18], float M1[18],
                                             const float V0[18], const float V1[18],
                                             const float fk[18], float* AbG, int l){
  #pragma unroll
  for(int k=0;k<18;k++){ M0[k]=V0[k]*fk[k]; M1[k]=V1[k]*fk[k]; }
  int base = threadIdx.x & 48;
  #pragma unroll
  for(int j=0;j<18;j++){
    float o0=0.f, o1=0.f;
    #pragma unroll
    for(int k=0;k<18;k++){
      float vj = __shfl((j<16)?V0[k]:V1[k], base+(j&15));
      o0 += M0[k]*vj;
      o1 += M1[k]*vj;
    }
    AbG[l*18+j]=o0;
    if(l<2) AbG[(l+16)*18+j]=o1;
  }
}

// scale C by a2, trace-normalize, +1e-5 I, congruence with W, logm -> store.
// One wave per block; 4 matrices per block (same m, consecutive (b,p)).
__global__ __launch_bounds__(64) void k_eighQKV(const float* __restrict__ Wq,
                                                const float* __restrict__ Wk,
                                                const float* __restrict__ Wv,
                                                float* __restrict__ ws){
  __shared__ float Wl[360];
  __shared__ float Cm[420];   // 20x21
  __shared__ float Tt[378];   // 18x21
  __shared__ float Ab[1296];  // 4 x 324
  __shared__ float a2s[20];
  int wid=blockIdx.x, tid=threadIdx.x;
  int m = wid/768;
  int bp4 = (wid - m*768)*4;
  const float* W = (m==0)?Wq:((m==1)?Wk:Wv);
  for(int i=tid;i<360;i+=64) Wl[i]=W[i];
  if(tid<20) a2s[tid]=ws[OFF_A2+tid];
  __syncthreads();
  // prep: A_g = W^T C'_g W into Ab[g]
  for(int g=0; g<4; g++){
    const float* Cb = ws + OFF_C + (size_t)(bp4+g)*400;
    for(int idx=tid; idx<400; idx+=64){
      int i=idx/20, j=idx-i*20;
      Cm[i*21+j]=Cb[idx]*a2s[i]*a2s[j];
    }
    __syncthreads();
    float tr=0.f;
    #pragma unroll
    for(int i=0;i<20;i++) tr += Cm[i*21+i];
    float invtr = 1.f/tr;
    for(int idx=tid; idx<360; idx+=64){
      int a=idx/20, j=idx-a*20;
      float s=0.f;
      for(int i=0;i<20;i++){
        float cij = Cm[i*21+j]*invtr + ((i==j)?1e-5f:0.f);
        s += Wl[i*18+a]*cij;
      }
      Tt[a*21+j]=s;
    }
    __syncthreads();
    for(int idx=tid; idx<324; idx+=64){
      int a=idx/18, c=idx-a*18;
      float s=0.f;
      for(int j=0;j<20;j++) s += Tt[a*21+j]*Wl[j*18+c];
      Ab[g*324+idx]=s;
    }
    __syncthreads();
  }
  // register-resident one-sided Jacobi (4 matrices in parallel across the wave)
  int l = tid & 15, g = tid >> 4;
  float* AbG = &Ab[g*324];
  float M0[18],M1[18],V0[18],V1[18],dg[18];
  #pragma unroll
  for(int k=0;k<18;k++){
    M0[k] = 0.5f*(AbG[l*18+k] + AbG[k*18+l]);                       // row l, symmetrized
    M1[k] = (l<2) ? 0.5f*(AbG[(l+16)*18+k] + AbG[k*18+l+16]) : 0.f; // row l+16
    V0[k] = (k==l)?1.f:0.f;
    V1[k] = (l<2 && k==l+16)?1.f:0.f;
  }
  onesided18(M0,M1,V0,V1,dg,11);
  float fk[18];
  #pragma unroll
  for(int k=0;k<18;k++) fk[k] = 0.5f*logf(fmaxf(dg[k],1e-24f));  // log(lambda)
  spectral_out(M0,M1,V0,V1,fk,AbG,l);
  __syncthreads();
  float* ob = ws + ((m==0)?OFF_LQ:((m==1)?OFF_LK:OFF_LV)) + (size_t)bp4*324;
  for(int idx=tid; idx<1296; idx+=64) ob[idx]=Ab[idx];
}

// energies, softmax over K-index, mean_log = sum_i prob * logV
__global__ __launch_bounds__(64) void k_att(float* __restrict__ ws){
  __shared__ float lq[972], lk[972];
  __shared__ float e[9];
  __shared__ float prob[3][3];
  int b=blockIdx.x, tid=threadIdx.x;
  const float* LQ=ws+OFF_LQ+(size_t)b*972;
  const float* LK=ws+OFF_LK+(size_t)b*972;
  for(int idx=tid; idx<972; idx+=64){ lq[idx]=LQ[idx]; lk[idx]=LK[idx]; }
  __syncthreads();
  if(tid<9){
    int i=tid/3, p=tid-i*3;
    const float* ki=lk+i*324; const float* qp=lq+p*324;
    float s=0.f;
    for(int el=0;el<324;el++){ float d=ki[el]-qp[el]; s+=d*d; }
    e[tid]=s;
  }
  __syncthreads();
  if(tid<3){
    float f0=1.f/(1.f+log1pf(e[0+tid]));
    float f1=1.f/(1.f+log1pf(e[3+tid]));
    float f2=1.f/(1.f+log1pf(e[6+tid]));
    float mx=fmaxf(f0,fmaxf(f1,f2));
    float x0=expf(f0-mx), x1=expf(f1-mx), x2=expf(f2-mx);
    float inv=1.f/(x0+x1+x2);
    prob[tid][0]=x0*inv; prob[tid][1]=x1*inv; prob[tid][2]=x2*inv;
  }
  __syncthreads();
  const float* LV=ws+OFF_LV+(size_t)b*972;
  float* ML=ws+OFF_ML+(size_t)b*972;
  for(int idx=tid; idx<972; idx+=64){
    int p=idx/324, el=idx-p*324;
    ML[idx]=prob[p][0]*LV[el]+prob[p][1]*LV[324+el]+prob[p][2]*LV[648+el];
  }
}

// eigh(mean_log + 12I) via one-sided SPD Jacobi (spectrum of mean_log is in
// [ln 1e-5, 1e-5] so the +12 shift is provably SPD); tang-eigvals = max(s,-9.21);
// triu features.
__global__ __launch_bounds__(64) void k_eigh2(float* __restrict__ ws){
  __shared__ float Ab[1296];
  int wid=blockIdx.x, tid=threadIdx.x;
  const float* ML = ws + OFF_ML + (size_t)wid*1296;
  for(int idx=tid; idx<1296; idx+=64) Ab[idx]=ML[idx];
  __syncthreads();
  int l = tid & 15, g = tid >> 4;
  float* AbG = &Ab[g*324];
  float M0[18],M1[18],V0[18],V1[18],dg[18];
  #pragma unroll
  for(int k=0;k<18;k++){
    float a0 = 0.5f*(AbG[l*18+k] + AbG[k*18+l]);
    if(k==l) a0 += 12.f;
    M0[k]=a0;
    float a1 = (l<2) ? 0.5f*(AbG[(l+16)*18+k] + AbG[k*18+l+16]) : 0.f;
    if(l<2 && k==l+16) a1 += 12.f;
    M1[k]=a1;
    V0[k] = (k==l)?1.f:0.f;
    V1[k] = (l<2 && k==l+16)?1.f:0.f;
  }
  onesided18(M0,M1,V0,V1,dg,9);
  float fk[18];
  #pragma unroll
  for(int k=0;k<18;k++) fk[k] = fmaxf(sqrtf(dg[k])-12.f, -9.2103404f);
  spectral_out(M0,M1,V0,V1,fk,AbG,l);
  __syncthreads();
  // triu extract -> feat (bp = wid*4+g2, feat offset bp*171, contiguous 684)
  float* fb = ws + OFF_FEAT + (size_t)wid*684;
  for(int idx=tid; idx<684; idx+=64){
    int g2=idx/171, t=idx-g2*171;
    int i=0, r=t;
    while(true){ int c=18-i; if(r<c) break; r-=c; i++; }
    int j=i+r;
    fb[idx]=Ab[g2*324 + i*18 + j];
  }
}

__global__ __launch_bounds__(256) void k_lin(const float* __restrict__ lw,
                                             const float* __restrict__ lb,
                                             const float* __restrict__ ws,
                                             float* __restrict__ out){
  int t=blockIdx.x*256+threadIdx.x;
  if(t>=B_*4) return;
  int b=t>>2, j=t&3;
  const float* f=ws+OFF_FEAT+(size_t)b*513;
  const float* w=lw+j*513;
  float s=lb[j];
  for(int k=0;k<513;k++) s+=f[k]*w[k];
  out[t]=s;
}

extern "C" void kernel_launch(void* const* d_in, const int* in_sizes, int n_in,
                              void* d_out, int out_size, void* d_ws, size_t ws_size,
                              hipStream_t stream){
  const float* x  =(const float*)d_in[0];
  const float* w1 =(const float*)d_in[1];
  const float* cb1=(const float*)d_in[2];
  const float* g1 =(const float*)d_in[3];
  const float* bb1=(const float*)d_in[4];
  const float* w2 =(const float*)d_in[5];
  // d_in[6] conv2_b, d_in[8] bn2_b: provably cancel (centering / variance invariance)
  const float* g2 =(const float*)d_in[7];
  const float* Wq =(const float*)d_in[9];
  const float* Wk =(const float*)d_in[10];
  const float* Wv =(const float*)d_in[11];
  const float* lw =(const float*)d_in[12];
  const float* lb =(const float*)d_in[13];
  float* ws=(float*)d_ws;
  float* out=(float*)d_out;

  k_zero<<<1,256,0,stream>>>(ws);
  k_moment<<<B_,256,0,stream>>>(x,ws);
  k_fin1<<<1,64,0,stream>>>(w1,cb1,g1,bb1,ws);
  k_conv2cov<<<B_,256,0,stream>>>(x,w1,w2,ws);
  k_fin2<<<1,64,0,stream>>>(g2,ws);
  k_eighQKV<<<2304,64,0,stream>>>(Wq,Wk,Wv,ws);
  k_att<<<B_,64,0,stream>>>(ws);
  k_eigh2<<<768,64,0,stream>>>(ws);
  k_lin<<<(B_*4+255)/256,256,0,stream>>>(lw,lb,ws,out);
}

// Round 4
// 1205.611 us; speedup vs baseline: 1.9653x; 1.1311x over previous
//
#include <hip/hip_runtime.h>
#include <cmath>

#define B_ 1024
#define CIN_ 22
#define T1_ 438
#define COUT_ 20
#define T2_ 439

// ws float offsets (total ~23 MB required)
#define OFF_S 0
#define OFF_M 32
#define OFF_A1 520
#define OFF_E1 544
#define OFF_SUM2 576
#define OFF_SSQ2 608
#define OFF_A2 640
#define OFF_ACC_END 704
#define OFF_C 1024
#define OFF_LQ (OFF_C + B_*3*400)
#define OFF_LK (OFF_LQ + B_*3*324)
#define OFF_LV (OFF_LK + B_*3*324)
#define OFF_ML (OFF_LV + B_*3*324)
#define OFF_FEAT (OFF_ML + B_*3*324)
#define WS_FLOATS (OFF_FEAT + B_*513)

__global__ __launch_bounds__(256) void k_zero(float* ws){
  for(int i=threadIdx.x; i<OFF_ACC_END; i+=256) ws[i]=0.f;
}

// bn1 stats via second-moment matrix of x: S[22], M[22][22] (triu)
__global__ __launch_bounds__(256) void k_moment(const float* __restrict__ x, float* __restrict__ ws){
  __shared__ float xs[CIN_*T1_];
  int b=blockIdx.x;
  const float* xb = x + (size_t)b*CIN_*T1_;
  for(int i=threadIdx.x;i<CIN_*T1_;i+=256) xs[i]=xb[i];
  __syncthreads();
  for(int tgt=threadIdx.x; tgt<275; tgt+=256){
    if(tgt<253){
      int r=tgt, i=0;
      while(true){ int c=CIN_-i; if(r<c) break; r-=c; i++; }
      int j=i+r;
      const float* ri=xs+i*T1_; const float* rj=xs+j*T1_;
      float acc=0.f;
      for(int t=0;t<T1_;t++) acc += ri[t]*rj[t];
      atomicAdd(&ws[OFF_M + i*CIN_ + j], acc);
    } else {
      int c=tgt-253;
      const float* rc=xs+c*T1_;
      float acc=0.f;
      for(int t=0;t<T1_;t++) acc += rc[t];
      atomicAdd(&ws[OFF_S + c], acc);
    }
  }
}

__global__ void k_fin1(const float* __restrict__ w1, const float* __restrict__ cb1,
                       const float* __restrict__ g1, const float* __restrict__ bb1,
                       float* __restrict__ ws){
  int c=threadIdx.x;
  if(c>=CIN_) return;
  const double N = (double)B_*T1_;
  double wS=0.0, wMw=0.0;
  for(int h=0;h<CIN_;h++) wS += (double)w1[c*CIN_+h]*(double)ws[OFF_S+h];
  for(int h=0;h<CIN_;h++){
    for(int h2=0;h2<CIN_;h2++){
      int i=h<h2?h:h2, j=h<h2?h2:h;
      wMw += (double)w1[c*CIN_+h]*(double)w1[c*CIN_+h2]*(double)ws[OFF_M+i*CIN_+j];
    }
  }
  double bc=cb1[c];
  double mean=wS/N+bc;
  double ex2=(wMw+2.0*bc*wS)/N+bc*bc;
  double var=ex2-mean*mean;
  double a1=(double)g1[c]/sqrt(var+1e-5);
  double d1=(double)bb1[c]-mean*a1;
  ws[OFF_A1+c]=(float)a1;            // y = a1*conv1 + e1
  ws[OFF_E1+c]=(float)(a1*bc+d1);
}

// per-batch: y = bn1(conv1(x)); h2 = conv2(y); raw patch covariances + bn2 sums
__global__ __launch_bounds__(256) void k_conv2cov(const float* __restrict__ x,
                                                  const float* __restrict__ w1,
                                                  const float* __restrict__ w2,
                                                  float* __restrict__ ws){
  __shared__ float yw[CIN_][160];
  __shared__ float h2w[COUT_][148];
  __shared__ float w2s[COUT_*CIN_*12];
  __shared__ float w1s[CIN_*CIN_];
  __shared__ float a1s[CIN_], e1s[CIN_];
  __shared__ float acc1[COUT_], acc2[COUT_], pmu[COUT_];
  int b=blockIdx.x, tid=threadIdx.x;
  for(int i=tid;i<COUT_*CIN_*12;i+=256) w2s[i]=w2[i];
  for(int i=tid;i<CIN_*CIN_;i+=256) w1s[i]=w1[i];
  if(tid<CIN_){ a1s[tid]=ws[OFF_A1+tid]; e1s[tid]=ws[OFF_E1+tid]; }
  if(tid<COUT_){ acc1[tid]=0.f; acc2[tid]=0.f; }
  __syncthreads();
  for(int p=0;p<3;p++){
    int off = (p==0)?0:((p==1)?147:293);
    int L = (p==0)?147:146;
    int ycols = L+11;
    int ybase = off-6;
    for(int idx=tid; idx<CIN_*ycols; idx+=256){
      int c=idx/ycols, tt=idx-c*ycols, gt=ybase+tt;
      float v=0.f;
      if(gt>=0 && gt<T1_){
        const float* xb=x+(size_t)b*CIN_*T1_+gt;
        float s=0.f;
        for(int h=0;h<CIN_;h++) s += w1s[c*CIN_+h]*xb[(size_t)h*T1_];
        v = a1s[c]*s + e1s[c];
      }
      yw[c][tt]=v;
    }
    __syncthreads();
    for(int idx=tid; idx<COUT_*L; idx+=256){
      int o=idx/L, tt=idx-o*L;
      float s=0.f;
      for(int i=0;i<CIN_;i++){
        const float* wo=&w2s[(o*CIN_+i)*12];
        const float* yr=&yw[i][tt];
        #pragma unroll
        for(int k=0;k<12;k++) s += wo[k]*yr[k];
      }
      h2w[o][tt]=s;
    }
    __syncthreads();
    if(tid<COUT_){
      float s1=0.f,s2=0.f;
      for(int t=0;t<L;t++){ float v=h2w[tid][t]; s1+=v; s2+=v*v; }
      acc1[tid]+=s1; acc2[tid]+=s2; pmu[tid]=s1/(float)L;
    }
    __syncthreads();
    float* Cb = ws + OFF_C + ((size_t)b*3+p)*400;
    for(int pp=tid; pp<210; pp+=256){
      int r=pp, i=0;
      while(true){ int c=COUT_-i; if(r<c) break; r-=c; i++; }
      int j=i+r;
      float s=0.f;
      for(int t=0;t<L;t++) s += h2w[i][t]*h2w[j][t];
      s -= (float)L*pmu[i]*pmu[j];
      Cb[i*COUT_+j]=s;
      Cb[j*COUT_+i]=s;
    }
    __syncthreads();
  }
  if(tid<COUT_){
    atomicAdd(&ws[OFF_SUM2+tid], acc1[tid]);
    atomicAdd(&ws[OFF_SSQ2+tid], acc2[tid]);
  }
}

__global__ void k_fin2(const float* __restrict__ g2, float* __restrict__ ws){
  int c=threadIdx.x; if(c>=COUT_) return;
  const double N=(double)B_*T2_;
  double m=ws[OFF_SUM2+c]/N;
  double v=ws[OFF_SSQ2+c]/N - m*m;
  ws[OFF_A2+c]=(float)((double)g2[c]/sqrt(v+1e-5));
}

// ---------------------------------------------------------------------------
// One-sided Jacobi for SPD 18x18, register-resident, V-FREE.
// Key property: starting from symmetric SPD A and applying right rotations
// until columns are orthogonal, the final columns are m_k = lambda_k * u_k.
// So eigenvalues = column norms and eigenvectors = normalized columns — no
// accumulated-V needed. State per lane: M0[18], M1[18], dg[18] = 54 floats
// (fits VGPRs; R2's V-carrying version overflowed into AGPR copy churn).
// 16-lane group per matrix, 4 matrices per wave. Lane l holds rows l, l+16.
// Column dots via shfl_xor butterflies (masks 1,2,4,8 stay inside the group).
// Round-robin pairs kept static by cyclic register renaming (3 arrays now).
// NOTE: no min-waves in __launch_bounds__ (R1 lesson: 4 w/EU hint -> spill).
// ---------------------------------------------------------------------------
__device__ __forceinline__ void onesided18(float M0[18], float M1[18],
                                           float dg[18], int maxsweep){
  for(int sweep=0; sweep<maxsweep; sweep++){
    // refresh column norms^2 (kills drift of the incremental updates)
    #pragma unroll
    for(int k=0;k<18;k++){
      float v = M0[k]*M0[k] + M1[k]*M1[k];
      v += __shfl_xor(v,1); v += __shfl_xor(v,2);
      v += __shfl_xor(v,4); v += __shfl_xor(v,8);
      dg[k]=v;
    }
    float smax=0.f;
    for(int r=0;r<17;r++){
      #pragma unroll
      for(int T=0;T<9;T++){
        const int p=T, q=(T==0)?17:(17-T);
        // apq = <col p, col q>, identical (bitwise) in all lanes of the group
        float v = M0[p]*M0[q] + M1[p]*M1[q];
        v += __shfl_xor(v,1); v += __shfl_xor(v,2);
        v += __shfl_xor(v,4); v += __shfl_xor(v,8);
        float app=dg[p], aqq=dg[q];
        float tau = __fdividef(aqq-app, 2.f*v);
        float tt  = __fdividef(copysignf(1.f,tau), fabsf(tau)+sqrtf(1.f+tau*tau));
        float c   = rsqrtf(1.f+tt*tt);
        float s   = tt*c;
        bool  z   = (v==0.f);
        tt = z?0.f:tt; c = z?1.f:c; s = z?0.f:s;
        dg[p]=app-tt*v; dg[q]=aqq+tt*v;
        smax=fmaxf(smax,fabsf(s));
        float x,y;
        x=M0[p]; y=M0[q]; M0[p]=c*x-s*y; M0[q]=s*x+c*y;
        x=M1[p]; y=M1[q]; M1[p]=c*x-s*y; M1[q]=s*x+c*y;
      }
      // cyclic rename of columns 0..16 (col 17 is the fixed tournament seat);
      // 17 renames/sweep = identity, so column order is restored each sweep.
      {
        float t0=M0[0],t1=M1[0],t4=dg[0];
        #pragma unroll
        for(int k=0;k<16;k++){
          M0[k]=M0[k+1]; M1[k]=M1[k+1]; dg[k]=dg[k+1];
        }
        M0[16]=t0; M1[16]=t1; dg[16]=t4;
      }
    }
    if(__all(smax < 1e-5f)) break;
  }
  // final exact column norms^2
  #pragma unroll
  for(int k=0;k<18;k++){
    float v = M0[k]*M0[k] + M1[k]*M1[k];
    v += __shfl_xor(v,1); v += __shfl_xor(v,2);
    v += __shfl_xor(v,4); v += __shfl_xor(v,8);
    dg[k]=v;
  }
}

// out = sum_k m_k g_k m_k^T  (g_k = f(lambda_k)/dg_k), written into AbG.
// Shfl source is M itself; g broadcast-shared between the two row halves.
__device__ __forceinline__ void spectral_out(const float M0[18], const float M1[18],
                                             const float g[18], float* AbG, int l){
  int base = threadIdx.x & 48;
  #pragma unroll
  for(int j=0;j<18;j++){
    float o0=0.f, o1=0.f;
    #pragma unroll
    for(int k=0;k<18;k++){
      float vj = __shfl((j<16)?M0[k]:M1[k], base+(j&15));
      float t = g[k]*vj;
      o0 += M0[k]*t;
      o1 += M1[k]*t;
    }
    AbG[l*18+j]=o0;
    if(l<2) AbG[(l+16)*18+j]=o1;
  }
}

// scale C by a2, trace-normalize, +1e-5 I, congruence with W, logm -> store.
// One wave per block; 4 matrices per block (same m, consecutive (b,p)).
__global__ __launch_bounds__(64) void k_eighQKV(const float* __restrict__ Wq,
                                                const float* __restrict__ Wk,
                                                const float* __restrict__ Wv,
                                                float* __restrict__ ws){
  __shared__ float Wl[360];
  __shared__ float Cm[420];   // 20x21
  __shared__ float Tt[378];   // 18x21
  __shared__ float Ab[1296];  // 4 x 324
  __shared__ float a2s[20];
  int wid=blockIdx.x, tid=threadIdx.x;
  int m = wid/768;
  int bp4 = (wid - m*768)*4;
  const float* W = (m==0)?Wq:((m==1)?Wk:Wv);
  for(int i=tid;i<360;i+=64) Wl[i]=W[i];
  if(tid<20) a2s[tid]=ws[OFF_A2+tid];
  __syncthreads();
  // prep: A_g = W^T C'_g W into Ab[g]
  for(int g=0; g<4; g++){
    const float* Cb = ws + OFF_C + (size_t)(bp4+g)*400;
    for(int idx=tid; idx<400; idx+=64){
      int i=idx/20, j=idx-i*20;
      Cm[i*21+j]=Cb[idx]*a2s[i]*a2s[j];
    }
    __syncthreads();
    float tr=0.f;
    #pragma unroll
    for(int i=0;i<20;i++) tr += Cm[i*21+i];
    float invtr = 1.f/tr;
    for(int idx=tid; idx<360; idx+=64){
      int a=idx/20, j=idx-a*20;
      float s=0.f;
      for(int i=0;i<20;i++){
        float cij = Cm[i*21+j]*invtr + ((i==j)?1e-5f:0.f);
        s += Wl[i*18+a]*cij;
      }
      Tt[a*21+j]=s;
    }
    __syncthreads();
    for(int idx=tid; idx<324; idx+=64){
      int a=idx/18, c=idx-a*18;
      float s=0.f;
      for(int j=0;j<20;j++) s += Tt[a*21+j]*Wl[j*18+c];
      Ab[g*324+idx]=s;
    }
    __syncthreads();
  }
  // register-resident one-sided Jacobi (4 matrices in parallel across the wave)
  int l = tid & 15, g = tid >> 4;
  float* AbG = &Ab[g*324];
  float M0[18],M1[18],dg[18];
  #pragma unroll
  for(int k=0;k<18;k++){
    M0[k] = 0.5f*(AbG[l*18+k] + AbG[k*18+l]);                       // row l, symmetrized
    M1[k] = (l<2) ? 0.5f*(AbG[(l+16)*18+k] + AbG[k*18+l+16]) : 0.f; // row l+16
  }
  onesided18(M0,M1,dg,11);
  #pragma unroll
  for(int k=0;k<18;k++){
    float lam2 = fmaxf(dg[k],1e-24f);
    dg[k] = __fdividef(0.5f*logf(lam2), lam2);   // g = log(lambda)/lambda^2
  }
  spectral_out(M0,M1,dg,AbG,l);
  __syncthreads();
  float* ob = ws + ((m==0)?OFF_LQ:((m==1)?OFF_LK:OFF_LV)) + (size_t)bp4*324;
  for(int idx=tid; idx<1296; idx+=64) ob[idx]=Ab[idx];
}

// energies, softmax over K-index, mean_log = sum_i prob * logV
__global__ __launch_bounds__(64) void k_att(float* __restrict__ ws){
  __shared__ float lq[972], lk[972];
  __shared__ float e[9];
  __shared__ float prob[3][3];
  int b=blockIdx.x, tid=threadIdx.x;
  const float* LQ=ws+OFF_LQ+(size_t)b*972;
  const float* LK=ws+OFF_LK+(size_t)b*972;
  for(int idx=tid; idx<972; idx+=64){ lq[idx]=LQ[idx]; lk[idx]=LK[idx]; }
  __syncthreads();
  if(tid<9){
    int i=tid/3, p=tid-i*3;
    const float* ki=lk+i*324; const float* qp=lq+p*324;
    float s=0.f;
    for(int el=0;el<324;el++){ float d=ki[el]-qp[el]; s+=d*d; }
    e[tid]=s;
  }
  __syncthreads();
  if(tid<3){
    float f0=1.f/(1.f+log1pf(e[0+tid]));
    float f1=1.f/(1.f+log1pf(e[3+tid]));
    float f2=1.f/(1.f+log1pf(e[6+tid]));
    float mx=fmaxf(f0,fmaxf(f1,f2));
    float x0=expf(f0-mx), x1=expf(f1-mx), x2=expf(f2-mx);
    float inv=1.f/(x0+x1+x2);
    prob[tid][0]=x0*inv; prob[tid][1]=x1*inv; prob[tid][2]=x2*inv;
  }
  __syncthreads();
  const float* LV=ws+OFF_LV+(size_t)b*972;
  float* ML=ws+OFF_ML+(size_t)b*972;
  for(int idx=tid; idx<972; idx+=64){
    int p=idx/324, el=idx-p*324;
    ML[idx]=prob[p][0]*LV[el]+prob[p][1]*LV[324+el]+prob[p][2]*LV[648+el];
  }
}

// eigh(mean_log + 12I) via V-free one-sided SPD Jacobi (spectrum of mean_log
// is in [ln 1e-5, ~0] so the +12 shift is provably SPD); tang-eigvals =
// max(sqrt(dg)-12, ln 1e-4); triu features.
__global__ __launch_bounds__(64) void k_eigh2(float* __restrict__ ws){
  __shared__ float Ab[1296];
  int wid=blockIdx.x, tid=threadIdx.x;
  const float* ML = ws + OFF_ML + (size_t)wid*1296;
  for(int idx=tid; idx<1296; idx+=64) Ab[idx]=ML[idx];
  __syncthreads();
  int l = tid & 15, g = tid >> 4;
  float* AbG = &Ab[g*324];
  float M0[18],M1[18],dg[18];
  #pragma unroll
  for(int k=0;k<18;k++){
    float a0 = 0.5f*(AbG[l*18+k] + AbG[k*18+l]);
    if(k==l) a0 += 12.f;
    M0[k]=a0;
    float a1 = (l<2) ? 0.5f*(AbG[(l+16)*18+k] + AbG[k*18+l+16]) : 0.f;
    if(l<2 && k==l+16) a1 += 12.f;
    M1[k]=a1;
  }
  onesided18(M0,M1,dg,9);
  #pragma unroll
  for(int k=0;k<18;k++){
    float lam = sqrtf(dg[k]);
    dg[k] = __fdividef(fmaxf(lam-12.f,-9.2103404f), dg[k]);  // g = f(lam)/lam^2
  }
  spectral_out(M0,M1,dg,AbG,l);
  __syncthreads();
  // triu extract -> feat (bp = wid*4+g2, feat offset bp*171, contiguous 684)
  float* fb = ws + OFF_FEAT + (size_t)wid*684;
  for(int idx=tid; idx<684; idx+=64){
    int g2=idx/171, t=idx-g2*171;
    int i=0, r=t;
    while(true){ int c=18-i; if(r<c) break; r-=c; i++; }
    int j=i+r;
    fb[idx]=Ab[g2*324 + i*18 + j];
  }
}

__global__ __launch_bounds__(256) void k_lin(const float* __restrict__ lw,
                                             const float* __restrict__ lb,
                                             const float* __restrict__ ws,
                                             float* __restrict__ out){
  int t=blockIdx.x*256+threadIdx.x;
  if(t>=B_*4) return;
  int b=t>>2, j=t&3;
  const float* f=ws+OFF_FEAT+(size_t)b*513;
  const float* w=lw+j*513;
  float s=lb[j];
  for(int k=0;k<513;k++) s+=f[k]*w[k];
  out[t]=s;
}

extern "C" void kernel_launch(void* const* d_in, const int* in_sizes, int n_in,
                              void* d_out, int out_size, void* d_ws, size_t ws_size,
                              hipStream_t stream){
  const float* x  =(const float*)d_in[0];
  const float* w1 =(const float*)d_in[1];
  const float* cb1=(const float*)d_in[2];
  const float* g1 =(const float*)d_in[3];
  const float* bb1=(const float*)d_in[4];
  const float* w2 =(const float*)d_in[5];
  // d_in[6] conv2_b, d_in[8] bn2_b: provably cancel (centering / variance invariance)
  const float* g2 =(const float*)d_in[7];
  const float* Wq =(const float*)d_in[9];
  const float* Wk =(const float*)d_in[10];
  const float* Wv =(const float*)d_in[11];
  const float* lw =(const float*)d_in[12];
  const float* lb =(const float*)d_in[13];
  float* ws=(float*)d_ws;
  float* out=(float*)d_out;

  k_zero<<<1,256,0,stream>>>(ws);
  k_moment<<<B_,256,0,stream>>>(x,ws);
  k_fin1<<<1,64,0,stream>>>(w1,cb1,g1,bb1,ws);
  k_conv2cov<<<B_,256,0,stream>>>(x,w1,w2,ws);
  k_fin2<<<1,64,0,stream>>>(g2,ws);
  k_eighQKV<<<2304,64,0,stream>>>(Wq,Wk,Wv,ws);
  k_att<<<B_,64,0,stream>>>(ws);
  k_eigh2<<<768,64,0,stream>>>(ws);
  k_lin<<<(B_*4+255)/256,256,0,stream>>>(lw,lb,ws,out);
}

// Round 5
// 766.183 us; speedup vs baseline: 3.0925x; 1.5735x over previous
//
#include <hip/hip_runtime.h>
#include <cmath>

#define B_ 1024
#define CIN_ 22
#define T1_ 438
#define COUT_ 20
#define T2_ 439

// ws float offsets (total ~23 MB required)
#define OFF_S 0
#define OFF_M 32
#define OFF_A1 520
#define OFF_E1 544
#define OFF_SUM2 576
#define OFF_SSQ2 608
#define OFF_A2 640
#define OFF_ACC_END 704
#define OFF_C 1024
#define OFF_LQ (OFF_C + B_*3*400)
#define OFF_LK (OFF_LQ + B_*3*324)
#define OFF_LV (OFF_LK + B_*3*324)
#define OFF_ML (OFF_LV + B_*3*324)
#define OFF_FEAT (OFF_ML + B_*3*324)
#define WS_FLOATS (OFF_FEAT + B_*513)

__global__ __launch_bounds__(256) void k_zero(float* ws){
  for(int i=threadIdx.x; i<OFF_ACC_END; i+=256) ws[i]=0.f;
}

// bn1 stats via second-moment matrix of x: S[22], M[22][22] (triu)
__global__ __launch_bounds__(256) void k_moment(const float* __restrict__ x, float* __restrict__ ws){
  __shared__ float xs[CIN_*T1_];
  int b=blockIdx.x;
  const float* xb = x + (size_t)b*CIN_*T1_;
  for(int i=threadIdx.x;i<CIN_*T1_;i+=256) xs[i]=xb[i];
  __syncthreads();
  for(int tgt=threadIdx.x; tgt<275; tgt+=256){
    if(tgt<253){
      int r=tgt, i=0;
      while(true){ int c=CIN_-i; if(r<c) break; r-=c; i++; }
      int j=i+r;
      const float* ri=xs+i*T1_; const float* rj=xs+j*T1_;
      float acc=0.f;
      for(int t=0;t<T1_;t++) acc += ri[t]*rj[t];
      atomicAdd(&ws[OFF_M + i*CIN_ + j], acc);
    } else {
      int c=tgt-253;
      const float* rc=xs+c*T1_;
      float acc=0.f;
      for(int t=0;t<T1_;t++) acc += rc[t];
      atomicAdd(&ws[OFF_S + c], acc);
    }
  }
}

__global__ void k_fin1(const float* __restrict__ w1, const float* __restrict__ cb1,
                       const float* __restrict__ g1, const float* __restrict__ bb1,
                       float* __restrict__ ws){
  int c=threadIdx.x;
  if(c>=CIN_) return;
  const double N = (double)B_*T1_;
  double wS=0.0, wMw=0.0;
  for(int h=0;h<CIN_;h++) wS += (double)w1[c*CIN_+h]*(double)ws[OFF_S+h];
  for(int h=0;h<CIN_;h++){
    for(int h2=0;h2<CIN_;h2++){
      int i=h<h2?h:h2, j=h<h2?h2:h;
      wMw += (double)w1[c*CIN_+h]*(double)w1[c*CIN_+h2]*(double)ws[OFF_M+i*CIN_+j];
    }
  }
  double bc=cb1[c];
  double mean=wS/N+bc;
  double ex2=(wMw+2.0*bc*wS)/N+bc*bc;
  double var=ex2-mean*mean;
  double a1=(double)g1[c]/sqrt(var+1e-5);
  double d1=(double)bb1[c]-mean*a1;
  ws[OFF_A1+c]=(float)a1;            // y = a1*conv1 + e1
  ws[OFF_E1+c]=(float)(a1*bc+d1);
}

// per-batch: y = bn1(conv1(x)); h2 = conv2(y); raw patch covariances + bn2 sums
__global__ __launch_bounds__(256) void k_conv2cov(const float* __restrict__ x,
                                                  const float* __restrict__ w1,
                                                  const float* __restrict__ w2,
                                                  float* __restrict__ ws){
  __shared__ float yw[CIN_][160];
  __shared__ float h2w[COUT_][148];
  __shared__ float w2s[COUT_*CIN_*12];
  __shared__ float w1s[CIN_*CIN_];
  __shared__ float a1s[CIN_], e1s[CIN_];
  __shared__ float acc1[COUT_], acc2[COUT_], pmu[COUT_];
  int b=blockIdx.x, tid=threadIdx.x;
  for(int i=tid;i<COUT_*CIN_*12;i+=256) w2s[i]=w2[i];
  for(int i=tid;i<CIN_*CIN_;i+=256) w1s[i]=w1[i];
  if(tid<CIN_){ a1s[tid]=ws[OFF_A1+tid]; e1s[tid]=ws[OFF_E1+tid]; }
  if(tid<COUT_){ acc1[tid]=0.f; acc2[tid]=0.f; }
  __syncthreads();
  for(int p=0;p<3;p++){
    int off = (p==0)?0:((p==1)?147:293);
    int L = (p==0)?147:146;
    int ycols = L+11;
    int ybase = off-6;
    for(int idx=tid; idx<CIN_*ycols; idx+=256){
      int c=idx/ycols, tt=idx-c*ycols, gt=ybase+tt;
      float v=0.f;
      if(gt>=0 && gt<T1_){
        const float* xb=x+(size_t)b*CIN_*T1_+gt;
        float s=0.f;
        for(int h=0;h<CIN_;h++) s += w1s[c*CIN_+h]*xb[(size_t)h*T1_];
        v = a1s[c]*s + e1s[c];
      }
      yw[c][tt]=v;
    }
    __syncthreads();
    for(int idx=tid; idx<COUT_*L; idx+=256){
      int o=idx/L, tt=idx-o*L;
      float s=0.f;
      for(int i=0;i<CIN_;i++){
        const float* wo=&w2s[(o*CIN_+i)*12];
        const float* yr=&yw[i][tt];
        #pragma unroll
        for(int k=0;k<12;k++) s += wo[k]*yr[k];
      }
      h2w[o][tt]=s;
    }
    __syncthreads();
    if(tid<COUT_){
      float s1=0.f,s2=0.f;
      for(int t=0;t<L;t++){ float v=h2w[tid][t]; s1+=v; s2+=v*v; }
      acc1[tid]+=s1; acc2[tid]+=s2; pmu[tid]=s1/(float)L;
    }
    __syncthreads();
    float* Cb = ws + OFF_C + ((size_t)b*3+p)*400;
    for(int pp=tid; pp<210; pp+=256){
      int r=pp, i=0;
      while(true){ int c=COUT_-i; if(r<c) break; r-=c; i++; }
      int j=i+r;
      float s=0.f;
      for(int t=0;t<L;t++) s += h2w[i][t]*h2w[j][t];
      s -= (float)L*pmu[i]*pmu[j];
      Cb[i*COUT_+j]=s;
      Cb[j*COUT_+i]=s;
    }
    __syncthreads();
  }
  if(tid<COUT_){
    atomicAdd(&ws[OFF_SUM2+tid], acc1[tid]);
    atomicAdd(&ws[OFF_SSQ2+tid], acc2[tid]);
  }
}

__global__ void k_fin2(const float* __restrict__ g2, float* __restrict__ ws){
  int c=threadIdx.x; if(c>=COUT_) return;
  const double N=(double)B_*T2_;
  double m=ws[OFF_SUM2+c]/N;
  double v=ws[OFF_SSQ2+c]/N - m*m;
  ws[OFF_A2+c]=(float)((double)g2[c]/sqrt(v+1e-5));
}

// ---------------------------------------------------------------------------
// Brent-Luk one-sided Jacobi for SPD 18x18, columns-in-lanes.
// 9 lanes per matrix (tournament seats), 7 matrices per wave (63/64 lanes).
// Lane l9 owns two full columns P (slot l9) and Q (slot l9==0?17:17-l9) in
// registers — apq/rotations are LOCAL (no cross-lane in the hot math).
// Round-robin = fixed per-round column migration (derived from the verified
// slot-shift: slot k<-k+1 for k=0..15, slot16<-slot0, slot17 pinned):
//   newP(lane T<=7) = lane T+1's P;  newP(lane 8) = own Q
//   newQ(lane 1)    = lane 0's P;    newQ(lane T>=2) = lane T-1's Q; lane0 keeps Q
// After 17 rounds (one sweep) columns return to their home slots.
// V-free eigenpairs: converged columns m_k = lambda_k u_k (A symmetric),
// f(A) = sum_k m_k (f(l_k)/l_k^2) m_k^T.  (R1 lesson: no min-waves hint.)
// ---------------------------------------------------------------------------
__device__ __forceinline__ void bl_jacobi(float P[18], float Q[18],
                                          float &dgp, float &dgq,
                                          int l9, int srcP, int srcQ, int maxsweep){
  for(int sweep=0; sweep<maxsweep; sweep++){
    // refresh column norms^2 (local — columns are lane-resident)
    float n0=0.f,n1=0.f,m0=0.f,m1=0.f;
    #pragma unroll
    for(int k=0;k<18;k+=2){
      n0 += P[k]*P[k];   n1 += P[k+1]*P[k+1];
      m0 += Q[k]*Q[k];   m1 += Q[k+1]*Q[k+1];
    }
    dgp = n0+n1; dgq = m0+m1;
    float smax = 0.f;
    for(int r=0;r<17;r++){
      float a0=0.f,a1=0.f;
      #pragma unroll
      for(int k=0;k<18;k+=2){ a0 += P[k]*Q[k]; a1 += P[k+1]*Q[k+1]; }
      float apq = a0+a1;
      float tau = __fdividef(dgq-dgp, 2.f*apq);
      float tt  = __fdividef(copysignf(1.f,tau), fabsf(tau)+sqrtf(1.f+tau*tau));
      float c   = rsqrtf(1.f+tt*tt);
      float s   = tt*c;
      bool  z   = (apq==0.f);
      tt = z?0.f:tt; c = z?1.f:c; s = z?0.f:s;
      float ndgp = dgp - tt*apq;
      float ndgq = dgq + tt*apq;
      smax = fmaxf(smax, fabsf(s));
      // rotate + migrate, fused per element
      #pragma unroll
      for(int k=0;k<18;k++){
        float x=P[k], y=Q[k];
        float rp = c*x - s*y;
        float rq = s*x + c*y;
        float np = __shfl(rp, srcP);
        np = (l9==8) ? rq : np;
        float sq = (l9==0) ? rp : rq;
        float nq = __shfl(sq, srcQ);
        P[k] = np;
        Q[k] = (l9==0) ? rq : nq;
      }
      { // dg values travel with their columns
        float np = __shfl(ndgp, srcP);
        np = (l9==8) ? ndgq : np;
        float sq = (l9==0) ? ndgp : ndgq;
        float nq = __shfl(sq, srcQ);
        dgp = np;
        dgq = (l9==0) ? ndgq : nq;
      }
    }
    if(__all(smax < 1e-5f)) break;
  }
  // final exact norms^2 = eigenvalues^2
  float n0=0.f,n1=0.f,m0=0.f,m1=0.f;
  #pragma unroll
  for(int k=0;k<18;k+=2){
    n0 += P[k]*P[k];   n1 += P[k+1]*P[k+1];
    m0 += Q[k]*Q[k];   m1 += Q[k+1]*Q[k+1];
  }
  dgp = n0+n1; dgq = m0+m1;
}

// scale C by a2, trace-normalize, +1e-5 I, congruence with W, logm -> store.
// One wave per block; 7 matrices per block, id = m*3072 + (b*3+p).
__global__ __launch_bounds__(64) void k_eighQKV(const float* __restrict__ Wq,
                                                const float* __restrict__ Wk,
                                                const float* __restrict__ Wv,
                                                float* __restrict__ ws){
  __shared__ float Wl[1080];   // Wq|Wk|Wv
  __shared__ float a2s[20];
  __shared__ float Cm[420];    // 20x21 staging
  __shared__ float Tt[378];    // 18x21
  __shared__ float Af[324];    // one prepped A at a time
  __shared__ float Mc[2520];   // 7 x [18 rows][20] column-transpose store
  __shared__ float gl[126];    // 7 x 18 spectral weights
  int blk=blockIdx.x, tid=threadIdx.x;
  int g = tid/9, l9 = tid - 9*g;              // g==7 -> idle lane 63
  int srcP = min(g*9 + ((l9==8)?8:(l9+1)), 63);
  int srcQ = g*9 + ((l9==0)?0:(l9-1));
  int ps = l9, qs = (l9==0)?17:(17-l9);

  for(int i=tid;i<1080;i+=64)
    Wl[i] = (i<360)?Wq[i]:((i<720)?Wk[i-360]:Wv[i-720]);
  if(tid<20) a2s[tid]=ws[OFF_A2+tid];
  __syncthreads();

  float P[18], Q[18], dgp, dgq;
  #pragma unroll
  for(int k=0;k<18;k++){ P[k]=0.f; Q[k]=0.f; }

  // prep each matrix; owning 9-lane group grabs its columns
  for(int gp_=0; gp_<7; gp_++){
    int id = min(blk*7+gp_, 9215);
    int m = id/3072, bp = id - m*3072;
    const float* Cb = ws + OFF_C + (size_t)bp*400;
    const float* Wm = Wl + m*360;
    for(int idx=tid; idx<400; idx+=64){
      int i=idx/20, j=idx-i*20;
      Cm[i*21+j]=Cb[idx]*a2s[i]*a2s[j];
    }
    __syncthreads();
    float tr=0.f;
    #pragma unroll
    for(int i=0;i<20;i++) tr += Cm[i*21+i];
    float invtr = 1.f/tr;
    for(int idx=tid; idx<360; idx+=64){
      int a=idx/20, j=idx-a*20;
      float s=0.f;
      for(int i=0;i<20;i++){
        float cij = Cm[i*21+j]*invtr + ((i==j)?1e-5f:0.f);
        s += Wm[i*18+a]*cij;
      }
      Tt[a*21+j]=s;
    }
    __syncthreads();
    for(int idx=tid; idx<324; idx+=64){
      int a=idx/18, c=idx-a*18;
      float s=0.f;
      for(int j=0;j<20;j++) s += Tt[a*21+j]*Wm[j*18+c];
      Af[idx]=s;
    }
    __syncthreads();
    if(g==gp_){
      #pragma unroll
      for(int k=0;k<18;k++){
        P[k] = 0.5f*(Af[k*18+ps] + Af[ps*18+k]);
        Q[k] = 0.5f*(Af[k*18+qs] + Af[qs*18+k]);
      }
    }
    __syncthreads();
  }

  bl_jacobi(P,Q,dgp,dgq,l9,srcP,srcQ,11);

  // spectral weights g = log(lambda)/lambda^2 = 0.5*log(dg)/dg
  float lp2 = fmaxf(dgp,1e-24f), lq2 = fmaxf(dgq,1e-24f);
  float gpv = __fdividef(0.5f*logf(lp2), lp2);
  float gqv = __fdividef(0.5f*logf(lq2), lq2);

  if(g<7){
    #pragma unroll
    for(int k=0;k<18;k++){
      Mc[g*360 + k*20 + ps] = P[k];
      Mc[g*360 + k*20 + qs] = Q[k];
    }
    gl[g*18+ps]=gpv; gl[g*18+qs]=gqv;
  }
  __syncthreads();

  // out[i][j] = sum_k gl[k] * Mc[i][k] * Mc[j][k]
  for(int idx=tid; idx<126; idx+=64){
    int mat=idx/18, i=idx-mat*18;
    int id = blk*7+mat;
    if(id<9216){
      int m=id/3072, bp=id-m*3072;
      float w[18];
      #pragma unroll
      for(int k=0;k<18;k++) w[k]=gl[mat*18+k]*Mc[mat*360+i*20+k];
      float* ob = ws + ((m==0)?OFF_LQ:((m==1)?OFF_LK:OFF_LV)) + (size_t)bp*324 + i*18;
      for(int j=0;j<18;j++){
        float s=0.f;
        #pragma unroll
        for(int k=0;k<18;k++) s += w[k]*Mc[mat*360+j*20+k];
        ob[j]=s;
      }
    }
  }
}

// energies, softmax over K-index, mean_log = sum_i prob * logV
__global__ __launch_bounds__(64) void k_att(float* __restrict__ ws){
  __shared__ float lq[972], lk[972];
  __shared__ float e[9];
  __shared__ float prob[3][3];
  int b=blockIdx.x, tid=threadIdx.x;
  const float* LQ=ws+OFF_LQ+(size_t)b*972;
  const float* LK=ws+OFF_LK+(size_t)b*972;
  for(int idx=tid; idx<972; idx+=64){ lq[idx]=LQ[idx]; lk[idx]=LK[idx]; }
  __syncthreads();
  if(tid<9){
    int i=tid/3, p=tid-i*3;
    const float* ki=lk+i*324; const float* qp=lq+p*324;
    float s=0.f;
    for(int el=0;el<324;el++){ float d=ki[el]-qp[el]; s+=d*d; }
    e[tid]=s;
  }
  __syncthreads();
  if(tid<3){
    float f0=1.f/(1.f+log1pf(e[0+tid]));
    float f1=1.f/(1.f+log1pf(e[3+tid]));
    float f2=1.f/(1.f+log1pf(e[6+tid]));
    float mx=fmaxf(f0,fmaxf(f1,f2));
    float x0=expf(f0-mx), x1=expf(f1-mx), x2=expf(f2-mx);
    float inv=1.f/(x0+x1+x2);
    prob[tid][0]=x0*inv; prob[tid][1]=x1*inv; prob[tid][2]=x2*inv;
  }
  __syncthreads();
  const float* LV=ws+OFF_LV+(size_t)b*972;
  float* ML=ws+OFF_ML+(size_t)b*972;
  for(int idx=tid; idx<972; idx+=64){
    int p=idx/324, el=idx-p*324;
    ML[idx]=prob[p][0]*LV[el]+prob[p][1]*LV[324+el]+prob[p][2]*LV[648+el];
  }
}

// eigh(mean_log + 12I) via Brent-Luk (spectrum of mean_log in [ln 1e-5, ~0]
// so +12 shift is SPD); tang-eigvals = max(sqrt(dg)-12, ln 1e-4); triu feat.
__global__ __launch_bounds__(64) void k_eigh2(float* __restrict__ ws){
  __shared__ float Mc[2520];   // phase 1: flat A staging (2268); phase 2: column store
  __shared__ float gl[126];
  int blk=blockIdx.x, tid=threadIdx.x;
  int g = tid/9, l9 = tid - 9*g;
  int srcP = min(g*9 + ((l9==8)?8:(l9+1)), 63);
  int srcQ = g*9 + ((l9==0)?0:(l9-1));
  int ps = l9, qs = (l9==0)?17:(17-l9);

  for(int idx=tid; idx<2268; idx+=64){
    int mg=idx/324, r=idx-mg*324;
    int rid = min(blk*7+mg, 3071);
    Mc[idx] = ws[OFF_ML + (size_t)rid*324 + r];
  }
  __syncthreads();

  float P[18], Q[18], dgp, dgq;
  if(g<7){
    const float* Ag = Mc + g*324;
    #pragma unroll
    for(int k=0;k<18;k++){
      P[k] = 0.5f*(Ag[k*18+ps] + Ag[ps*18+k]) + ((k==ps)?12.f:0.f);
      Q[k] = 0.5f*(Ag[k*18+qs] + Ag[qs*18+k]) + ((k==qs)?12.f:0.f);
    }
  } else {
    #pragma unroll
    for(int k=0;k<18;k++){ P[k]=0.f; Q[k]=0.f; }
  }
  __syncthreads();

  bl_jacobi(P,Q,dgp,dgq,l9,srcP,srcQ,9);

  float lp = sqrtf(dgp), lq = sqrtf(dgq);
  float gpv = __fdividef(fmaxf(lp-12.f,-9.2103404f), fmaxf(dgp,1e-12f));
  float gqv = __fdividef(fmaxf(lq-12.f,-9.2103404f), fmaxf(dgq,1e-12f));

  if(g<7){
    #pragma unroll
    for(int k=0;k<18;k++){
      Mc[g*360 + k*20 + ps] = P[k];
      Mc[g*360 + k*20 + qs] = Q[k];
    }
    gl[g*18+ps]=gpv; gl[g*18+qs]=gqv;
  }
  __syncthreads();

  // triu(tang) -> feat
  for(int idx=tid; idx<126; idx+=64){
    int mat=idx/18, i=idx-mat*18;
    int id = blk*7+mat;
    if(id<3072){
      float w[18];
      #pragma unroll
      for(int k=0;k<18;k++) w[k]=gl[mat*18+k]*Mc[mat*360+i*20+k];
      float* fb = ws + OFF_FEAT + (size_t)id*171 + (i*18 - (i*(i-1))/2) - i;
      for(int j=i;j<18;j++){
        float s=0.f;
        #pragma unroll
        for(int k=0;k<18;k++) s += w[k]*Mc[mat*360+j*20+k];
        fb[j]=s;
      }
    }
  }
}

__global__ __launch_bounds__(256) void k_lin(const float* __restrict__ lw,
                                             const float* __restrict__ lb,
                                             const float* __restrict__ ws,
                                             float* __restrict__ out){
  int t=blockIdx.x*256+threadIdx.x;
  if(t>=B_*4) return;
  int b=t>>2, j=t&3;
  const float* f=ws+OFF_FEAT+(size_t)b*513;
  const float* w=lw+j*513;
  float s=lb[j];
  for(int k=0;k<513;k++) s+=f[k]*w[k];
  out[t]=s;
}

extern "C" void kernel_launch(void* const* d_in, const int* in_sizes, int n_in,
                              void* d_out, int out_size, void* d_ws, size_t ws_size,
                              hipStream_t stream){
  const float* x  =(const float*)d_in[0];
  const float* w1 =(const float*)d_in[1];
  const float* cb1=(const float*)d_in[2];
  const float* g1 =(const float*)d_in[3];
  const float* bb1=(const float*)d_in[4];
  const float* w2 =(const float*)d_in[5];
  // d_in[6] conv2_b, d_in[8] bn2_b: provably cancel (centering / variance invariance)
  const float* g2 =(const float*)d_in[7];
  const float* Wq =(const float*)d_in[9];
  const float* Wk =(const float*)d_in[10];
  const float* Wv =(const float*)d_in[11];
  const float* lw =(const float*)d_in[12];
  const float* lb =(const float*)d_in[13];
  float* ws=(float*)d_ws;
  float* out=(float*)d_out;

  k_zero<<<1,256,0,stream>>>(ws);
  k_moment<<<B_,256,0,stream>>>(x,ws);
  k_fin1<<<1,64,0,stream>>>(w1,cb1,g1,bb1,ws);
  k_conv2cov<<<B_,256,0,stream>>>(x,w1,w2,ws);
  k_fin2<<<1,64,0,stream>>>(g2,ws);
  k_eighQKV<<<1317,64,0,stream>>>(Wq,Wk,Wv,ws);   // 1317*7 >= 9216 matrices
  k_att<<<B_,64,0,stream>>>(ws);
  k_eigh2<<<439,64,0,stream>>>(ws);               // 439*7 >= 3072 matrices
  k_lin<<<(B_*4+255)/256,256,0,stream>>>(lw,lb,ws,out);
}

// Round 6
// 563.271 us; speedup vs baseline: 4.2065x; 1.3602x over previous
//
#include <hip/hip_runtime.h>
#include <cmath>

#define B_ 1024
#define CIN_ 22
#define T1_ 438
#define COUT_ 20
#define T2_ 439

// ws float offsets (total ~23 MB required)
#define OFF_S 0
#define OFF_M 32
#define OFF_SUM2 576
#define OFF_SSQ2 608
#define OFF_A2 640
#define OFF_ACC_END 704
#define OFF_C 1024
#define OFF_LQ (OFF_C + B_*3*400)
#define OFF_LK (OFF_LQ + B_*3*324)
#define OFF_LV (OFF_LK + B_*3*324)
#define OFF_ML (OFF_LV + B_*3*324)
#define OFF_FEAT (OFF_ML + B_*3*324)
#define OFF_WEFF (OFF_FEAT + B_*513)
#define OFF_BPRE (OFF_WEFF + 5280)

__global__ __launch_bounds__(256) void k_zero(float* ws){
  for(int i=threadIdx.x; i<OFF_ACC_END; i+=256) ws[i]=0.f;
}

// bn1 stats via second-moment matrix of x: S[22], M[22][22] (triu), float4 dots
__global__ __launch_bounds__(256) void k_moment(const float* __restrict__ x, float* __restrict__ ws){
  __shared__ float xs[CIN_][440];
  int b=blockIdx.x;
  const float* xb = x + (size_t)b*CIN_*T1_;
  for(int i=threadIdx.x;i<CIN_*T1_;i+=256){
    int h=i/T1_, t=i-h*T1_;
    xs[h][t]=xb[i];
  }
  if(threadIdx.x<CIN_){ xs[threadIdx.x][438]=0.f; xs[threadIdx.x][439]=0.f; }
  __syncthreads();
  for(int tgt=threadIdx.x; tgt<275; tgt+=256){
    if(tgt<253){
      int r=tgt, i=0;
      while(true){ int c=CIN_-i; if(r<c) break; r-=c; i++; }
      int j=i+r;
      const float4* ri=(const float4*)&xs[i][0];
      const float4* rj=(const float4*)&xs[j][0];
      float acc=0.f;
      for(int t=0;t<110;t++){
        float4 a=ri[t], bb=rj[t];
        acc += a.x*bb.x + a.y*bb.y + a.z*bb.z + a.w*bb.w;
      }
      atomicAdd(&ws[OFF_M + i*CIN_ + j], acc);
    } else {
      int c=tgt-253;
      const float4* rc=(const float4*)&xs[c][0];
      float acc=0.f;
      for(int t=0;t<110;t++){
        float4 a=rc[t];
        acc += a.x + a.y + a.z + a.w;
      }
      atomicAdd(&ws[OFF_S + c], acc);
    }
  }
}

// bn1 closed-form + fold conv1/bn1 into conv2: Weff[o][h][k], bias prefix pre[o][13]
__global__ __launch_bounds__(256) void k_prep(const float* __restrict__ w1, const float* __restrict__ cb1,
                                              const float* __restrict__ g1, const float* __restrict__ bb1,
                                              const float* __restrict__ w2, float* __restrict__ ws){
  __shared__ float a1s[CIN_], e1s[CIN_];
  int tid=threadIdx.x;
  if(tid<CIN_){
    int c=tid;
    const double N = (double)B_*T1_;
    double wS=0.0, wMw=0.0;
    for(int h=0;h<CIN_;h++) wS += (double)w1[c*CIN_+h]*(double)ws[OFF_S+h];
    for(int h=0;h<CIN_;h++){
      for(int h2=0;h2<CIN_;h2++){
        int i=h<h2?h:h2, j=h<h2?h2:h;
        wMw += (double)w1[c*CIN_+h]*(double)w1[c*CIN_+h2]*(double)ws[OFF_M+i*CIN_+j];
      }
    }
    double bc=cb1[c];
    double mean=wS/N+bc;
    double ex2=(wMw+2.0*bc*wS)/N+bc*bc;
    double var=ex2-mean*mean;
    double a1=(double)g1[c]/sqrt(var+1e-5);
    double d1=(double)bb1[c]-mean*a1;
    a1s[c]=(float)a1;
    e1s[c]=(float)(a1*bc+d1);   // y = a1*(w1 x) + e1 inside [0,T1)
  }
  __syncthreads();
  // Weff[o][h][k] = sum_i w2[o][i][k]*a1[i]*w1[i][h]
  for(int idx=tid; idx<5280; idx+=256){
    int o=idx/264, r=idx-o*264, h=r/12, k=r-h*12;
    float s=0.f;
    for(int i=0;i<CIN_;i++) s += w2[(o*CIN_+i)*12+k]*a1s[i]*w1[i*CIN_+h];
    ws[OFF_WEFF+idx]=s;
  }
  // bias prefix: pre[o][k] = sum_{k'<k} (sum_i w2[o][i][k']*e1[i])
  if(tid<COUT_){
    float pre=0.f;
    ws[OFF_BPRE+tid*13+0]=0.f;
    for(int k=0;k<12;k++){
      float wb=0.f;
      for(int i=0;i<CIN_;i++) wb += w2[(tid*CIN_+i)*12+k]*e1s[i];
      pre += wb;
      ws[OFF_BPRE+tid*13+k+1]=pre;
    }
  }
}

// direct conv x->h2 (folded kernel) + per-patch covariance + bn2 sums.
// thread (o, chunk): 13 outputs, 24-elem x window in regs -> 156 FMA / 36 LDS reads.
// lane stride 13 floats is coprime with 32 banks -> conflict-free.
__global__ __launch_bounds__(256) void k_cov(const float* __restrict__ x,
                                             float* __restrict__ ws){
  __shared__ float Wl[5280];        // [o][h][k]
  __shared__ float preL[COUT_][13];
  __shared__ float xs[CIN_][168];
  __shared__ float h2w[COUT_][153];
  __shared__ float pmu[COUT_];
  int b=blockIdx.x, tid=threadIdx.x;
  for(int i=tid;i<5280;i+=256) Wl[i]=ws[OFF_WEFF+i];
  for(int i=tid;i<260;i+=256) ((float*)preL)[i]=ws[OFF_BPRE+i];
  int pi=0,pj=0;
  if(tid<210){ int r=tid,i=0; while(true){int c=COUT_-i; if(r<c)break; r-=c; i++;} pi=i; pj=i+r; }
  int sc = tid-210;                 // sum channel for tid in [210,230)
  float ac1=0.f, ac2=0.f;
  const float* xb = x + (size_t)b*CIN_*T1_;
  int o = tid/12, cch = tid-12*o;   // conv unit (tid<240)
  int t0 = cch*13;
  for(int p=0;p<3;p++){
    const int off = (p==0)?0:((p==1)?147:293);
    const int L = (p==0)?147:146;
    __syncthreads();
    for(int idx=tid; idx<CIN_*168; idx+=256){
      int h=idx/168, c2=idx-h*168;
      int gxt = off-6+c2;
      xs[h][c2] = (c2<167 && gxt>=0 && gxt<T1_) ? xb[h*T1_+gxt] : 0.f;
    }
    __syncthreads();
    if(tid<240){
      float acc[13];
      #pragma unroll
      for(int j=0;j<13;j++){
        int gt = off+t0+j;
        int kmin = 6-gt; kmin = kmin<0?0:kmin;
        int kmax = 443-gt; kmax = kmax>11?11:kmax;
        acc[j] = (kmax>=kmin)? preL[o][kmax+1]-preL[o][kmin] : 0.f;
      }
      const float* Wo = &Wl[o*264];
      for(int h=0;h<CIN_;h++){
        float xw[24];
        #pragma unroll
        for(int c2=0;c2<24;c2++) xw[c2]=xs[h][t0+c2];
        const float* Wh = Wo + h*12;
        #pragma unroll
        for(int k=0;k<12;k++){
          float w=Wh[k];
          #pragma unroll
          for(int j=0;j<13;j++) acc[j] += w*xw[j+k];
        }
      }
      #pragma unroll
      for(int j=0;j<13;j++) if(t0+j<L) h2w[o][t0+j]=acc[j];
    }
    __syncthreads();
    float s=0.f;
    if(tid<210){
      for(int t=0;t<L;t++) s += h2w[pi][t]*h2w[pj][t];
    } else if(sc>=0 && sc<COUT_){
      float s1=0.f,s2=0.f;
      for(int t=0;t<L;t++){ float v=h2w[sc][t]; s1+=v; s2+=v*v; }
      ac1+=s1; ac2+=s2; pmu[sc]=s1/(float)L;
    }
    __syncthreads();
    if(tid<210){
      s -= (float)L*pmu[pi]*pmu[pj];
      float* Cb = ws + OFF_C + ((size_t)b*3+p)*400;
      Cb[pi*COUT_+pj]=s; Cb[pj*COUT_+pi]=s;
    }
  }
  if(sc>=0 && sc<COUT_){
    atomicAdd(&ws[OFF_SUM2+sc], ac1);
    atomicAdd(&ws[OFF_SSQ2+sc], ac2);
  }
}

__global__ void k_fin2(const float* __restrict__ g2, float* __restrict__ ws){
  int c=threadIdx.x; if(c>=COUT_) return;
  const double N=(double)B_*T2_;
  double m=ws[OFF_SUM2+c]/N;
  double v=ws[OFF_SSQ2+c]/N - m*m;
  ws[OFF_A2+c]=(float)((double)g2[c]/sqrt(v+1e-5));
}

// ---------------------------------------------------------------------------
// Brent-Luk one-sided Jacobi for SPD 18x18, columns-in-lanes (see R5 notes).
// 9 lanes per matrix, 7 matrices per wave. V-free: converged cols = lambda*u.
// ---------------------------------------------------------------------------
__device__ __forceinline__ void bl_jacobi(float P[18], float Q[18],
                                          float &dgp, float &dgq,
                                          int l9, int srcP, int srcQ, int maxsweep){
  for(int sweep=0; sweep<maxsweep; sweep++){
    float n0=0.f,n1=0.f,m0=0.f,m1=0.f;
    #pragma unroll
    for(int k=0;k<18;k+=2){
      n0 += P[k]*P[k];   n1 += P[k+1]*P[k+1];
      m0 += Q[k]*Q[k];   m1 += Q[k+1]*Q[k+1];
    }
    dgp = n0+n1; dgq = m0+m1;
    float smax = 0.f;
    for(int r=0;r<17;r++){
      float a0=0.f,a1=0.f;
      #pragma unroll
      for(int k=0;k<18;k+=2){ a0 += P[k]*Q[k]; a1 += P[k+1]*Q[k+1]; }
      float apq = a0+a1;
      float tau = __fdividef(dgq-dgp, 2.f*apq);
      float tt  = __fdividef(copysignf(1.f,tau), fabsf(tau)+sqrtf(1.f+tau*tau));
      float c   = rsqrtf(1.f+tt*tt);
      float s   = tt*c;
      bool  z   = (apq==0.f);
      tt = z?0.f:tt; c = z?1.f:c; s = z?0.f:s;
      float ndgp = dgp - tt*apq;
      float ndgq = dgq + tt*apq;
      smax = fmaxf(smax, fabsf(s));
      #pragma unroll
      for(int k=0;k<18;k++){
        float x=P[k], y=Q[k];
        float rp = c*x - s*y;
        float rq = s*x + c*y;
        float np = __shfl(rp, srcP);
        np = (l9==8) ? rq : np;
        float sq = (l9==0) ? rp : rq;
        float nq = __shfl(sq, srcQ);
        P[k] = np;
        Q[k] = (l9==0) ? rq : nq;
      }
      {
        float np = __shfl(ndgp, srcP);
        np = (l9==8) ? ndgq : np;
        float sq = (l9==0) ? ndgp : ndgq;
        float nq = __shfl(sq, srcQ);
        dgp = np;
        dgq = (l9==0) ? ndgq : nq;
      }
    }
    if(__all(smax < 1e-5f)) break;
  }
  float n0=0.f,n1=0.f,m0=0.f,m1=0.f;
  #pragma unroll
  for(int k=0;k<18;k+=2){
    n0 += P[k]*P[k];   n1 += P[k+1]*P[k+1];
    m0 += Q[k]*Q[k];   m1 += Q[k+1]*Q[k+1];
  }
  dgp = n0+n1; dgq = m0+m1;
}

// scale C by a2, trace-normalize, +1e-5 I, congruence with W, logm -> store.
__global__ __launch_bounds__(64) void k_eighQKV(const float* __restrict__ Wq,
                                                const float* __restrict__ Wk,
                                                const float* __restrict__ Wv,
                                                float* __restrict__ ws){
  __shared__ float Wl[1080];
  __shared__ float a2s[20];
  __shared__ float Cm[420];
  __shared__ float Tt[378];
  __shared__ float Af[324];
  __shared__ float Mc[2520];
  __shared__ float gl[126];
  int blk=blockIdx.x, tid=threadIdx.x;
  int g = tid/9, l9 = tid - 9*g;
  int srcP = min(g*9 + ((l9==8)?8:(l9+1)), 63);
  int srcQ = g*9 + ((l9==0)?0:(l9-1));
  int ps = l9, qs = (l9==0)?17:(17-l9);

  for(int i=tid;i<1080;i+=64)
    Wl[i] = (i<360)?Wq[i]:((i<720)?Wk[i-360]:Wv[i-720]);
  if(tid<20) a2s[tid]=ws[OFF_A2+tid];
  __syncthreads();

  float P[18], Q[18], dgp, dgq;
  #pragma unroll
  for(int k=0;k<18;k++){ P[k]=0.f; Q[k]=0.f; }

  for(int gp_=0; gp_<7; gp_++){
    int id = min(blk*7+gp_, 9215);
    int m = id/3072, bp = id - m*3072;
    const float* Cb = ws + OFF_C + (size_t)bp*400;
    const float* Wm = Wl + m*360;
    for(int idx=tid; idx<400; idx+=64){
      int i=idx/20, j=idx-i*20;
      Cm[i*21+j]=Cb[idx]*a2s[i]*a2s[j];
    }
    __syncthreads();
    float tr=0.f;
    #pragma unroll
    for(int i=0;i<20;i++) tr += Cm[i*21+i];
    float invtr = 1.f/tr;
    for(int idx=tid; idx<360; idx+=64){
      int a=idx/20, j=idx-a*20;
      float s=0.f;
      for(int i=0;i<20;i++){
        float cij = Cm[i*21+j]*invtr + ((i==j)?1e-5f:0.f);
        s += Wm[i*18+a]*cij;
      }
      Tt[a*21+j]=s;
    }
    __syncthreads();
    for(int idx=tid; idx<324; idx+=64){
      int a=idx/18, c=idx-a*18;
      float s=0.f;
      for(int j=0;j<20;j++) s += Tt[a*21+j]*Wm[j*18+c];
      Af[idx]=s;
    }
    __syncthreads();
    if(g==gp_){
      #pragma unroll
      for(int k=0;k<18;k++){
        P[k] = 0.5f*(Af[k*18+ps] + Af[ps*18+k]);
        Q[k] = 0.5f*(Af[k*18+qs] + Af[qs*18+k]);
      }
    }
    __syncthreads();
  }

  bl_jacobi(P,Q,dgp,dgq,l9,srcP,srcQ,11);

  float lp2 = fmaxf(dgp,1e-24f), lq2 = fmaxf(dgq,1e-24f);
  float gpv = __fdividef(0.5f*logf(lp2), lp2);
  float gqv = __fdividef(0.5f*logf(lq2), lq2);

  if(g<7){
    #pragma unroll
    for(int k=0;k<18;k++){
      Mc[g*360 + k*20 + ps] = P[k];
      Mc[g*360 + k*20 + qs] = Q[k];
    }
    gl[g*18+ps]=gpv; gl[g*18+qs]=gqv;
  }
  __syncthreads();

  for(int idx=tid; idx<126; idx+=64){
    int mat=idx/18, i=idx-mat*18;
    int id = blk*7+mat;
    if(id<9216){
      int m=id/3072, bp=id-m*3072;
      float w[18];
      #pragma unroll
      for(int k=0;k<18;k++) w[k]=gl[mat*18+k]*Mc[mat*360+i*20+k];
      float* ob = ws + ((m==0)?OFF_LQ:((m==1)?OFF_LK:OFF_LV)) + (size_t)bp*324 + i*18;
      for(int j=0;j<18;j++){
        float s=0.f;
        #pragma unroll
        for(int k=0;k<18;k++) s += w[k]*Mc[mat*360+j*20+k];
        ob[j]=s;
      }
    }
  }
}

// energies, softmax over K-index, mean_log = sum_i prob * logV
__global__ __launch_bounds__(64) void k_att(float* __restrict__ ws){
  __shared__ float lq[972], lk[972];
  __shared__ float e[9];
  __shared__ float prob[3][3];
  int b=blockIdx.x, tid=threadIdx.x;
  const float* LQ=ws+OFF_LQ+(size_t)b*972;
  const float* LK=ws+OFF_LK+(size_t)b*972;
  for(int idx=tid; idx<972; idx+=64){ lq[idx]=LQ[idx]; lk[idx]=LK[idx]; }
  __syncthreads();
  if(tid<9){
    int i=tid/3, p=tid-i*3;
    const float* ki=lk+i*324; const float* qp=lq+p*324;
    float s=0.f;
    for(int el=0;el<324;el++){ float d=ki[el]-qp[el]; s+=d*d; }
    e[tid]=s;
  }
  __syncthreads();
  if(tid<3){
    float f0=1.f/(1.f+log1pf(e[0+tid]));
    float f1=1.f/(1.f+log1pf(e[3+tid]));
    float f2=1.f/(1.f+log1pf(e[6+tid]));
    float mx=fmaxf(f0,fmaxf(f1,f2));
    float x0=expf(f0-mx), x1=expf(f1-mx), x2=expf(f2-mx);
    float inv=1.f/(x0+x1+x2);
    prob[tid][0]=x0*inv; prob[tid][1]=x1*inv; prob[tid][2]=x2*inv;
  }
  __syncthreads();
  const float* LV=ws+OFF_LV+(size_t)b*972;
  float* ML=ws+OFF_ML+(size_t)b*972;
  for(int idx=tid; idx<972; idx+=64){
    int p=idx/324, el=idx-p*324;
    ML[idx]=prob[p][0]*LV[el]+prob[p][1]*LV[324+el]+prob[p][2]*LV[648+el];
  }
}

// eigh(mean_log + 12I) via Brent-Luk; tang-eigvals = max(sqrt(dg)-12, ln 1e-4); triu feat.
__global__ __launch_bounds__(64) void k_eigh2(float* __restrict__ ws){
  __shared__ float Mc[2520];
  __shared__ float gl[126];
  int blk=blockIdx.x, tid=threadIdx.x;
  int g = tid/9, l9 = tid - 9*g;
  int srcP = min(g*9 + ((l9==8)?8:(l9+1)), 63);
  int srcQ = g*9 + ((l9==0)?0:(l9-1));
  int ps = l9, qs = (l9==0)?17:(17-l9);

  for(int idx=tid; idx<2268; idx+=64){
    int mg=idx/324, r=idx-mg*324;
    int rid = min(blk*7+mg, 3071);
    Mc[idx] = ws[OFF_ML + (size_t)rid*324 + r];
  }
  __syncthreads();

  float P[18], Q[18], dgp, dgq;
  if(g<7){
    const float* Ag = Mc + g*324;
    #pragma unroll
    for(int k=0;k<18;k++){
      P[k] = 0.5f*(Ag[k*18+ps] + Ag[ps*18+k]) + ((k==ps)?12.f:0.f);
      Q[k] = 0.5f*(Ag[k*18+qs] + Ag[qs*18+k]) + ((k==qs)?12.f:0.f);
    }
  } else {
    #pragma unroll
    for(int k=0;k<18;k++){ P[k]=0.f; Q[k]=0.f; }
  }
  __syncthreads();

  bl_jacobi(P,Q,dgp,dgq,l9,srcP,srcQ,9);

  float lp = sqrtf(dgp), lq = sqrtf(dgq);
  float gpv = __fdividef(fmaxf(lp-12.f,-9.2103404f), fmaxf(dgp,1e-12f));
  float gqv = __fdividef(fmaxf(lq-12.f,-9.2103404f), fmaxf(dgq,1e-12f));

  if(g<7){
    #pragma unroll
    for(int k=0;k<18;k++){
      Mc[g*360 + k*20 + ps] = P[k];
      Mc[g*360 + k*20 + qs] = Q[k];
    }
    gl[g*18+ps]=gpv; gl[g*18+qs]=gqv;
  }
  __syncthreads();

  for(int idx=tid; idx<126; idx+=64){
    int mat=idx/18, i=idx-mat*18;
    int id = blk*7+mat;
    if(id<3072){
      float w[18];
      #pragma unroll
      for(int k=0;k<18;k++) w[k]=gl[mat*18+k]*Mc[mat*360+i*20+k];
      float* fb = ws + OFF_FEAT + (size_t)id*171 + (i*18 - (i*(i-1))/2) - i;
      for(int j=i;j<18;j++){
        float s=0.f;
        #pragma unroll
        for(int k=0;k<18;k++) s += w[k]*Mc[mat*360+j*20+k];
        fb[j]=s;
      }
    }
  }
}

__global__ __launch_bounds__(256) void k_lin(const float* __restrict__ lw,
                                             const float* __restrict__ lb,
                                             const float* __restrict__ ws,
                                             float* __restrict__ out){
  int t=blockIdx.x*256+threadIdx.x;
  if(t>=B_*4) return;
  int b=t>>2, j=t&3;
  const float* f=ws+OFF_FEAT+(size_t)b*513;
  const float* w=lw+j*513;
  float s=lb[j];
  for(int k=0;k<513;k++) s+=f[k]*w[k];
  out[t]=s;
}

extern "C" void kernel_launch(void* const* d_in, const int* in_sizes, int n_in,
                              void* d_out, int out_size, void* d_ws, size_t ws_size,
                              hipStream_t stream){
  const float* x  =(const float*)d_in[0];
  const float* w1 =(const float*)d_in[1];
  const float* cb1=(const float*)d_in[2];
  const float* g1 =(const float*)d_in[3];
  const float* bb1=(const float*)d_in[4];
  const float* w2 =(const float*)d_in[5];
  // d_in[6] conv2_b, d_in[8] bn2_b: provably cancel (centering / variance invariance)
  const float* g2 =(const float*)d_in[7];
  const float* Wq =(const float*)d_in[9];
  const float* Wk =(const float*)d_in[10];
  const float* Wv =(const float*)d_in[11];
  const float* lw =(const float*)d_in[12];
  const float* lb =(const float*)d_in[13];
  float* ws=(float*)d_ws;
  float* out=(float*)d_out;

  k_zero<<<1,256,0,stream>>>(ws);
  k_moment<<<B_,256,0,stream>>>(x,ws);
  k_prep<<<1,256,0,stream>>>(w1,cb1,g1,bb1,w2,ws);
  k_cov<<<B_,256,0,stream>>>(x,ws);
  k_fin2<<<1,64,0,stream>>>(g2,ws);
  k_eighQKV<<<1317,64,0,stream>>>(Wq,Wk,Wv,ws);   // 1317*7 >= 9216 matrices
  k_att<<<B_,64,0,stream>>>(ws);
  k_eigh2<<<439,64,0,stream>>>(ws);               // 439*7 >= 3072 matrices
  k_lin<<<(B_*4+255)/256,256,0,stream>>>(lw,lb,ws,out);
}

// Round 7
// 496.142 us; speedup vs baseline: 4.7757x; 1.1353x over previous
//
#include <hip/hip_runtime.h>
#include <cmath>

#define B_ 1024
#define CIN_ 22
#define T1_ 438
#define COUT_ 20
#define T2_ 439

// ws float offsets (total ~23 MB required)
#define OFF_S 0
#define OFF_M 32
#define OFF_SUM2 576
#define OFF_SSQ2 608
#define OFF_A2 640
#define OFF_ACC_END 704
#define OFF_C 1024
#define OFF_LQ (OFF_C + B_*3*400)
#define OFF_LK (OFF_LQ + B_*3*324)
#define OFF_LV (OFF_LK + B_*3*324)
#define OFF_ML (OFF_LV + B_*3*324)
#define OFF_FEAT (OFF_ML + B_*3*324)
#define OFF_WEFF (OFF_FEAT + B_*513)
#define OFF_BPRE (OFF_WEFF + 5280)

__global__ __launch_bounds__(256) void k_zero(float* ws){
  for(int i=threadIdx.x; i<OFF_ACC_END; i+=256) ws[i]=0.f;
}

// bn1 stats via second-moment matrix of x: S[22], M[22][22] (triu), float4 dots
__global__ __launch_bounds__(256) void k_moment(const float* __restrict__ x, float* __restrict__ ws){
  __shared__ float xs[CIN_][440];
  int b=blockIdx.x;
  const float* xb = x + (size_t)b*CIN_*T1_;
  for(int i=threadIdx.x;i<CIN_*T1_;i+=256){
    int h=i/T1_, t=i-h*T1_;
    xs[h][t]=xb[i];
  }
  if(threadIdx.x<CIN_){ xs[threadIdx.x][438]=0.f; xs[threadIdx.x][439]=0.f; }
  __syncthreads();
  for(int tgt=threadIdx.x; tgt<275; tgt+=256){
    if(tgt<253){
      int r=tgt, i=0;
      while(true){ int c=CIN_-i; if(r<c) break; r-=c; i++; }
      int j=i+r;
      const float4* ri=(const float4*)&xs[i][0];
      const float4* rj=(const float4*)&xs[j][0];
      float acc=0.f;
      for(int t=0;t<110;t++){
        float4 a=ri[t], bb=rj[t];
        acc += a.x*bb.x + a.y*bb.y + a.z*bb.z + a.w*bb.w;
      }
      atomicAdd(&ws[OFF_M + i*CIN_ + j], acc);
    } else {
      int c=tgt-253;
      const float4* rc=(const float4*)&xs[c][0];
      float acc=0.f;
      for(int t=0;t<110;t++){
        float4 a=rc[t];
        acc += a.x + a.y + a.z + a.w;
      }
      atomicAdd(&ws[OFF_S + c], acc);
    }
  }
}

// bn1 closed-form + fold conv1/bn1 into conv2: Weff[o][h][k], bias prefix pre[o][13]
__global__ __launch_bounds__(256) void k_prep(const float* __restrict__ w1, const float* __restrict__ cb1,
                                              const float* __restrict__ g1, const float* __restrict__ bb1,
                                              const float* __restrict__ w2, float* __restrict__ ws){
  __shared__ float a1s[CIN_], e1s[CIN_];
  int tid=threadIdx.x;
  if(tid<CIN_){
    int c=tid;
    const double N = (double)B_*T1_;
    double wS=0.0, wMw=0.0;
    for(int h=0;h<CIN_;h++) wS += (double)w1[c*CIN_+h]*(double)ws[OFF_S+h];
    for(int h=0;h<CIN_;h++){
      for(int h2=0;h2<CIN_;h2++){
        int i=h<h2?h:h2, j=h<h2?h2:h;
        wMw += (double)w1[c*CIN_+h]*(double)w1[c*CIN_+h2]*(double)ws[OFF_M+i*CIN_+j];
      }
    }
    double bc=cb1[c];
    double mean=wS/N+bc;
    double ex2=(wMw+2.0*bc*wS)/N+bc*bc;
    double var=ex2-mean*mean;
    double a1=(double)g1[c]/sqrt(var+1e-5);
    double d1=(double)bb1[c]-mean*a1;
    a1s[c]=(float)a1;
    e1s[c]=(float)(a1*bc+d1);   // y = a1*(w1 x) + e1 inside [0,T1)
  }
  __syncthreads();
  // Weff[o][h][k] = sum_i w2[o][i][k]*a1[i]*w1[i][h]
  for(int idx=tid; idx<5280; idx+=256){
    int o=idx/264, r=idx-o*264, h=r/12, k=r-h*12;
    float s=0.f;
    for(int i=0;i<CIN_;i++) s += w2[(o*CIN_+i)*12+k]*a1s[i]*w1[i*CIN_+h];
    ws[OFF_WEFF+idx]=s;
  }
  // bias prefix: pre[o][k] = sum_{k'<k} (sum_i w2[o][i][k']*e1[i])
  if(tid<COUT_){
    float pre=0.f;
    ws[OFF_BPRE+tid*13+0]=0.f;
    for(int k=0;k<12;k++){
      float wb=0.f;
      for(int i=0;i<CIN_;i++) wb += w2[(tid*CIN_+i)*12+k]*e1s[i];
      pre += wb;
      ws[OFF_BPRE+tid*13+k+1]=pre;
    }
  }
}

// direct conv x->h2 (folded kernel) + per-patch covariance + bn2 sums.
// thread (o, chunk): 13 outputs, 24-elem x window in regs -> 156 FMA / 36 LDS reads.
// cov dots vectorized float4 over zero-padded h2w rows (156 = 39*4).
__global__ __launch_bounds__(256) void k_cov(const float* __restrict__ x,
                                             float* __restrict__ ws){
  __shared__ float Wl[5280];        // [o][h][k]
  __shared__ float preL[COUT_][13];
  __shared__ float xs[CIN_][168];
  __shared__ float h2w[COUT_][156];
  __shared__ float pmu[COUT_];
  int b=blockIdx.x, tid=threadIdx.x;
  for(int i=tid;i<5280;i+=256) Wl[i]=ws[OFF_WEFF+i];
  for(int i=tid;i<260;i+=256) ((float*)preL)[i]=ws[OFF_BPRE+i];
  int pi=0,pj=0;
  if(tid<210){ int r=tid,i=0; while(true){int c=COUT_-i; if(r<c)break; r-=c; i++;} pi=i; pj=i+r; }
  int sc = tid-210;                 // sum channel for tid in [210,230)
  float ac1=0.f, ac2=0.f;
  const float* xb = x + (size_t)b*CIN_*T1_;
  int o = tid/12, cch = tid-12*o;   // conv unit (tid<240)
  int t0 = cch*13;
  for(int p=0;p<3;p++){
    const int off = (p==0)?0:((p==1)?147:293);
    const int L = (p==0)?147:146;
    __syncthreads();
    for(int idx=tid; idx<CIN_*168; idx+=256){
      int h=idx/168, c2=idx-h*168;
      int gxt = off-6+c2;
      xs[h][c2] = (c2<167 && gxt>=0 && gxt<T1_) ? xb[h*T1_+gxt] : 0.f;
    }
    __syncthreads();
    if(tid<240){
      float acc[13];
      #pragma unroll
      for(int j=0;j<13;j++){
        int gt = off+t0+j;
        int kmin = 6-gt; kmin = kmin<0?0:kmin;
        int kmax = 443-gt; kmax = kmax>11?11:kmax;
        acc[j] = (kmax>=kmin)? preL[o][kmax+1]-preL[o][kmin] : 0.f;
      }
      const float* Wo = &Wl[o*264];
      for(int h=0;h<CIN_;h++){
        float xw[24];
        #pragma unroll
        for(int c2=0;c2<24;c2++) xw[c2]=xs[h][t0+c2];
        const float* Wh = Wo + h*12;
        #pragma unroll
        for(int k=0;k<12;k++){
          float w=Wh[k];
          #pragma unroll
          for(int j=0;j<13;j++) acc[j] += w*xw[j+k];
        }
      }
      #pragma unroll
      for(int j=0;j<13;j++) if(t0+j<L) h2w[o][t0+j]=acc[j];
    } else {
      // zero-pad rows L..155 so float4 dots see zeros
      int npad = 156-L;
      for(int z=tid-240; z<COUT_*npad; z+=16){
        int oo=z/npad, c2=z-oo*npad;
        h2w[oo][L+c2]=0.f;
      }
    }
    __syncthreads();
    float s=0.f;
    if(tid<210){
      const float4* ri=(const float4*)&h2w[pi][0];
      const float4* rj=(const float4*)&h2w[pj][0];
      for(int t=0;t<39;t++){
        float4 a=ri[t], bb=rj[t];
        s += a.x*bb.x + a.y*bb.y + a.z*bb.z + a.w*bb.w;
      }
    } else if(sc>=0 && sc<COUT_){
      const float4* rc=(const float4*)&h2w[sc][0];
      float s1=0.f,s2=0.f;
      for(int t=0;t<39;t++){
        float4 a=rc[t];
        s1 += a.x+a.y+a.z+a.w;
        s2 += a.x*a.x+a.y*a.y+a.z*a.z+a.w*a.w;
      }
      ac1+=s1; ac2+=s2; pmu[sc]=s1/(float)L;
    }
    __syncthreads();
    if(tid<210){
      s -= (float)L*pmu[pi]*pmu[pj];
      float* Cb = ws + OFF_C + ((size_t)b*3+p)*400;
      Cb[pi*COUT_+pj]=s; Cb[pj*COUT_+pi]=s;
    }
  }
  if(sc>=0 && sc<COUT_){
    atomicAdd(&ws[OFF_SUM2+sc], ac1);
    atomicAdd(&ws[OFF_SSQ2+sc], ac2);
  }
}

__global__ void k_fin2(const float* __restrict__ g2, float* __restrict__ ws){
  int c=threadIdx.x; if(c>=COUT_) return;
  const double N=(double)B_*T2_;
  double m=ws[OFF_SUM2+c]/N;
  double v=ws[OFF_SSQ2+c]/N - m*m;
  ws[OFF_A2+c]=(float)((double)g2[c]/sqrt(v+1e-5));
}

// ---------------------------------------------------------------------------
// Brent-Luk one-sided Jacobi for SPD 18x18, columns-in-lanes (see R5/R6 notes).
// 9 lanes per matrix. V-free: converged cols = lambda*u.
// Exit threshold 3e-3: check runs AFTER the sweep is applied, so residual
// error ~ smax^2 ~ 1e-5 — one full sweep cheaper than the 1e-5 threshold.
// ---------------------------------------------------------------------------
__device__ __forceinline__ void bl_jacobi(float P[18], float Q[18],
                                          float &dgp, float &dgq,
                                          int l9, int srcP, int srcQ, int maxsweep){
  for(int sweep=0; sweep<maxsweep; sweep++){
    float n0=0.f,n1=0.f,m0=0.f,m1=0.f;
    #pragma unroll
    for(int k=0;k<18;k+=2){
      n0 += P[k]*P[k];   n1 += P[k+1]*P[k+1];
      m0 += Q[k]*Q[k];   m1 += Q[k+1]*Q[k+1];
    }
    dgp = n0+n1; dgq = m0+m1;
    float smax = 0.f;
    for(int r=0;r<17;r++){
      float a0=0.f,a1=0.f;
      #pragma unroll
      for(int k=0;k<18;k+=2){ a0 += P[k]*Q[k]; a1 += P[k+1]*Q[k+1]; }
      float apq = a0+a1;
      float tau = __fdividef(dgq-dgp, 2.f*apq);
      float tt  = __fdividef(copysignf(1.f,tau), fabsf(tau)+sqrtf(1.f+tau*tau));
      float c   = rsqrtf(1.f+tt*tt);
      float s   = tt*c;
      bool  z   = (apq==0.f);
      tt = z?0.f:tt; c = z?1.f:c; s = z?0.f:s;
      float ndgp = dgp - tt*apq;
      float ndgq = dgq + tt*apq;
      smax = fmaxf(smax, fabsf(s));
      #pragma unroll
      for(int k=0;k<18;k++){
        float x=P[k], y=Q[k];
        float rp = c*x - s*y;
        float rq = s*x + c*y;
        float np = __shfl(rp, srcP);
        np = (l9==8) ? rq : np;
        float sq = (l9==0) ? rp : rq;
        float nq = __shfl(sq, srcQ);
        P[k] = np;
        Q[k] = (l9==0) ? rq : nq;
      }
      {
        float np = __shfl(ndgp, srcP);
        np = (l9==8) ? ndgq : np;
        float sq = (l9==0) ? ndgp : ndgq;
        float nq = __shfl(sq, srcQ);
        dgp = np;
        dgq = (l9==0) ? ndgq : nq;
      }
    }
    if(__all(smax < 3e-3f)) break;
  }
  float n0=0.f,n1=0.f,m0=0.f,m1=0.f;
  #pragma unroll
  for(int k=0;k<18;k+=2){
    n0 += P[k]*P[k];   n1 += P[k+1]*P[k+1];
    m0 += Q[k]*Q[k];   m1 += Q[k+1]*Q[k+1];
  }
  dgp = n0+n1; dgq = m0+m1;
}

// scale C by a2, trace-normalize, +1e-5 I, congruence with W, logm -> store.
// 7 matrices per 1-wave block; OFF_LQ/LK/LV are contiguous so a block's
// 7 outputs form one contiguous span -> LDS-staged float4 coalesced copy.
__global__ __launch_bounds__(64) void k_eighQKV(const float* __restrict__ Wq,
                                                const float* __restrict__ Wk,
                                                const float* __restrict__ Wv,
                                                float* __restrict__ ws){
  __shared__ float Wl[1080];
  __shared__ float a2s[20];
  __shared__ float scratch[2268];  // prep: Cm(0,420)|Tt(420,378)|Af(800,324); out: 7x324
  __shared__ float Mc[2520];
  __shared__ float gl[126];
  int blk=blockIdx.x, tid=threadIdx.x;
  int g = tid/9, l9 = tid - 9*g;
  int srcP = min(g*9 + ((l9==8)?8:(l9+1)), 63);
  int srcQ = g*9 + ((l9==0)?0:(l9-1));
  int ps = l9, qs = (l9==0)?17:(17-l9);
  float* Cm = scratch;
  float* Tt = scratch+420;
  float* Af = scratch+800;

  for(int i=tid;i<1080;i+=64)
    Wl[i] = (i<360)?Wq[i]:((i<720)?Wk[i-360]:Wv[i-720]);
  if(tid<20) a2s[tid]=ws[OFF_A2+tid];
  __syncthreads();

  float P[18], Q[18], dgp, dgq;
  #pragma unroll
  for(int k=0;k<18;k++){ P[k]=0.f; Q[k]=0.f; }

  for(int gp_=0; gp_<7; gp_++){
    int id = min(blk*7+gp_, 9215);
    int m = id/3072, bp = id - m*3072;
    const float* Cb = ws + OFF_C + (size_t)bp*400;
    const float* Wm = Wl + m*360;
    for(int idx=tid; idx<400; idx+=64){
      int i=idx/20, j=idx-i*20;
      Cm[i*21+j]=Cb[idx]*a2s[i]*a2s[j];
    }
    __syncthreads();
    float tr=0.f;
    #pragma unroll
    for(int i=0;i<20;i++) tr += Cm[i*21+i];
    float invtr = 1.f/tr;
    for(int idx=tid; idx<360; idx+=64){
      int a=idx/20, j=idx-a*20;
      float s=0.f;
      for(int i=0;i<20;i++){
        float cij = Cm[i*21+j]*invtr + ((i==j)?1e-5f:0.f);
        s += Wm[i*18+a]*cij;
      }
      Tt[a*21+j]=s;
    }
    __syncthreads();
    for(int idx=tid; idx<324; idx+=64){
      int a=idx/18, c=idx-a*18;
      float s=0.f;
      for(int j=0;j<20;j++) s += Tt[a*21+j]*Wm[j*18+c];
      Af[idx]=s;
    }
    __syncthreads();
    if(g==gp_){
      #pragma unroll
      for(int k=0;k<18;k++){
        P[k] = 0.5f*(Af[k*18+ps] + Af[ps*18+k]);
        Q[k] = 0.5f*(Af[k*18+qs] + Af[qs*18+k]);
      }
    }
    __syncthreads();
  }

  bl_jacobi(P,Q,dgp,dgq,l9,srcP,srcQ,8);

  float lp2 = fmaxf(dgp,1e-24f), lq2 = fmaxf(dgq,1e-24f);
  float gpv = __fdividef(0.5f*logf(lp2), lp2);
  float gqv = __fdividef(0.5f*logf(lq2), lq2);

  if(g<7){
    #pragma unroll
    for(int k=0;k<18;k++){
      Mc[g*360 + k*20 + ps] = P[k];
      Mc[g*360 + k*20 + qs] = Q[k];
    }
    gl[g*18+ps]=gpv; gl[g*18+qs]=gqv;
  }
  __syncthreads();

  // out[i][j] = sum_k gl[k]*Mc[i][k]*Mc[j][k] -> scratch (LDS), then coalesced copy
  for(int idx=tid; idx<126; idx+=64){
    int mat=idx/18, i=idx-mat*18;
    float w[18];
    #pragma unroll
    for(int k=0;k<18;k++) w[k]=gl[mat*18+k]*Mc[mat*360+i*20+k];
    for(int j=0;j<18;j++){
      float s=0.f;
      #pragma unroll
      for(int k=0;k<18;k++) s += w[k]*Mc[mat*360+j*20+k];
      scratch[mat*324+i*18+j]=s;
    }
  }
  __syncthreads();
  int nmat = 9216 - blk*7; if(nmat>7) nmat=7;
  float4* gb4 = (float4*)(ws + OFF_LQ + (size_t)blk*7*324);
  const float4* sc4 = (const float4*)scratch;
  int cnt4 = nmat*81;
  for(int i=tid;i<cnt4;i+=64) gb4[i]=sc4[i];
}

// fused: energies + softmax + mean_log + eigh(+12I shift) + triu feat, 1 batch/block
__global__ __launch_bounds__(64) void k_att2(float* __restrict__ ws){
  __shared__ float lv[972];
  __shared__ float lqk[1944];   // lq | lk ; reused as ml after softmax
  __shared__ float e9[9];
  __shared__ float prob[9];
  __shared__ float Mc[1080];
  __shared__ float gl[54];
  int b=blockIdx.x, tid=threadIdx.x;
  const float4* LQ4=(const float4*)(ws+OFF_LQ+(size_t)b*972);
  const float4* LK4=(const float4*)(ws+OFF_LK+(size_t)b*972);
  const float4* LV4=(const float4*)(ws+OFF_LV+(size_t)b*972);
  float4* lqk4=(float4*)lqk; float4* lv4=(float4*)lv;
  for(int i=tid;i<243;i+=64){ lqk4[i]=LQ4[i]; lqk4[243+i]=LK4[i]; lv4[i]=LV4[i]; }
  __syncthreads();
  if(tid<36){
    int d=tid>>2, sub=tid&3;
    int ii=d/3, p=d-ii*3;
    const float* kk=lqk+972+ii*324+sub*81;
    const float* qq=lqk+p*324+sub*81;
    float s=0.f;
    for(int el=0;el<81;el++){ float dd=kk[el]-qq[el]; s+=dd*dd; }
    s += __shfl_xor(s,1); s += __shfl_xor(s,2);
    if(sub==0) e9[d]=s;
  }
  __syncthreads();
  if(tid<3){
    int p=tid;
    float f0=1.f/(1.f+log1pf(e9[0+p]));
    float f1=1.f/(1.f+log1pf(e9[3+p]));
    float f2=1.f/(1.f+log1pf(e9[6+p]));
    float mx=fmaxf(f0,fmaxf(f1,f2));
    float x0=expf(f0-mx), x1=expf(f1-mx), x2=expf(f2-mx);
    float inv=1.f/(x0+x1+x2);
    prob[p*3+0]=x0*inv; prob[p*3+1]=x1*inv; prob[p*3+2]=x2*inv;
  }
  __syncthreads();
  float* ml = lqk;   // overwrite (lq/lk dead after energies)
  for(int idx=tid; idx<972; idx+=64){
    int p=idx/324, el=idx-p*324;
    ml[idx]=prob[p*3+0]*lv[el]+prob[p*3+1]*lv[324+el]+prob[p*3+2]*lv[648+el];
  }
  __syncthreads();
  int g=tid/9, l9=tid-9*g;
  int srcP=min(g*9+((l9==8)?8:(l9+1)),63);
  int srcQ=g*9+((l9==0)?0:(l9-1));
  int ps=l9, qs=(l9==0)?17:(17-l9);
  float P[18],Q[18],dgp,dgq;
  if(g<3){
    const float* Ag=ml+g*324;
    #pragma unroll
    for(int k=0;k<18;k++){
      P[k]=0.5f*(Ag[k*18+ps]+Ag[ps*18+k]) + ((k==ps)?12.f:0.f);
      Q[k]=0.5f*(Ag[k*18+qs]+Ag[qs*18+k]) + ((k==qs)?12.f:0.f);
    }
  } else {
    #pragma unroll
    for(int k=0;k<18;k++){ P[k]=0.f; Q[k]=0.f; }
  }
  bl_jacobi(P,Q,dgp,dgq,l9,srcP,srcQ,8);
  float lp=sqrtf(dgp), lqv=sqrtf(dgq);
  float gpv=__fdividef(fmaxf(lp-12.f,-9.2103404f), fmaxf(dgp,1e-12f));
  float gqv=__fdividef(fmaxf(lqv-12.f,-9.2103404f), fmaxf(dgq,1e-12f));
  if(g<3){
    #pragma unroll
    for(int k=0;k<18;k++){
      Mc[g*360 + k*20 + ps]=P[k];
      Mc[g*360 + k*20 + qs]=Q[k];
    }
    gl[g*18+ps]=gpv; gl[g*18+qs]=gqv;
  }
  __syncthreads();
  // triu(tang) -> feat (same layout as before: (b*3+mat)*171)
  if(tid<54){
    int mat=tid/18, i=tid-mat*18;
    float w[18];
    #pragma unroll
    for(int k=0;k<18;k++) w[k]=gl[mat*18+k]*Mc[mat*360+i*20+k];
    float* fb = ws + OFF_FEAT + (size_t)b*513 + mat*171 + (i*18 - (i*(i-1))/2) - i;
    for(int j=i;j<18;j++){
      float s=0.f;
      #pragma unroll
      for(int k=0;k<18;k++) s += w[k]*Mc[mat*360+j*20+k];
      fb[j]=s;
    }
  }
}

__global__ __launch_bounds__(256) void k_lin(const float* __restrict__ lw,
                                             const float* __restrict__ lb,
                                             const float* __restrict__ ws,
                                             float* __restrict__ out){
  int t=blockIdx.x*256+threadIdx.x;
  if(t>=B_*4) return;
  int b=t>>2, j=t&3;
  const float* f=ws+OFF_FEAT+(size_t)b*513;
  const float* w=lw+j*513;
  float s=lb[j];
  for(int k=0;k<513;k++) s+=f[k]*w[k];
  out[t]=s;
}

extern "C" void kernel_launch(void* const* d_in, const int* in_sizes, int n_in,
                              void* d_out, int out_size, void* d_ws, size_t ws_size,
                              hipStream_t stream){
  const float* x  =(const float*)d_in[0];
  const float* w1 =(const float*)d_in[1];
  const float* cb1=(const float*)d_in[2];
  const float* g1 =(const float*)d_in[3];
  const float* bb1=(const float*)d_in[4];
  const float* w2 =(const float*)d_in[5];
  // d_in[6] conv2_b, d_in[8] bn2_b: provably cancel (centering / variance invariance)
  const float* g2 =(const float*)d_in[7];
  const float* Wq =(const float*)d_in[9];
  const float* Wk =(const float*)d_in[10];
  const float* Wv =(const float*)d_in[11];
  const float* lw =(const float*)d_in[12];
  const float* lb =(const float*)d_in[13];
  float* ws=(float*)d_ws;
  float* out=(float*)d_out;

  k_zero<<<1,256,0,stream>>>(ws);
  k_moment<<<B_,256,0,stream>>>(x,ws);
  k_prep<<<1,256,0,stream>>>(w1,cb1,g1,bb1,w2,ws);
  k_cov<<<B_,256,0,stream>>>(x,ws);
  k_fin2<<<1,64,0,stream>>>(g2,ws);
  k_eighQKV<<<1317,64,0,stream>>>(Wq,Wk,Wv,ws);   // 1317*7 >= 9216 matrices
  k_att2<<<B_,64,0,stream>>>(ws);                 // fused att + eigh2 + feat
  k_lin<<<(B_*4+255)/256,256,0,stream>>>(lw,lb,ws,out);
}